// Round 3
// baseline (2256.777 us; speedup 1.0000x reference)
//
#include <hip/hip_runtime.h>

typedef unsigned short u16;
typedef unsigned int   u32;
typedef __attribute__((ext_vector_type(2))) u32  u32x2;
typedef __attribute__((ext_vector_type(4))) u32  u32x4;
typedef __attribute__((ext_vector_type(8))) __bf16 bf16x8;
typedef __attribute__((ext_vector_type(4))) float  f32x4;

#define NN 20000
#define NE 320000
#define XD 131
#define H1 514
#define H1P 544
#define NCH 17

// wave-local wait: LDS (DS pipe) drained; needed at cross-lane write->read and
// read->overwrite boundaries since there are NO block barriers in these kernels.
#define LGKM0 asm volatile("s_waitcnt lgkmcnt(0)" ::: "memory")

__device__ __forceinline__ float silu(float a) { return a / (1.0f + __expf(-a)); }

__device__ __forceinline__ u16 f2bf(float f) {   // fp32 -> bf16 RNE (prep kernels)
    u32 u = __builtin_bit_cast(u32, f);
    return (u16)((u + 0x7FFFu + ((u >> 16) & 1u)) >> 16);
}

__device__ __forceinline__ u32 pk2(float a, float b) {  // pack 2 fp32 -> 2 bf16
    return (u32)__builtin_bit_cast(u16, (__bf16)a) |
           ((u32)__builtin_bit_cast(u16, (__bf16)b) << 16);
}

__device__ __forceinline__ bf16x8 mk8(u32 a, u32 b, u32 c, u32 d) {
    u32x4 t = {a, b, c, d};
    return __builtin_bit_cast(bf16x8, t);
}

__device__ __forceinline__ f32x4 mfma16(bf16x8 a, bf16x8 b, f32x4 c) {
    return __builtin_amdgcn_mfma_f32_16x16x32_bf16(a, b, c, 0, 0, 0);
}

// ---------------- weight prep (fp32 -> bf16 transposed, padded) ----------------

// w1b[l][n<544][k<256] row-major (512B rows) + bias2[l][n] = {eb1, w1_lastrow}
__global__ void prep_w1(const float* __restrict__ ew1, const float* __restrict__ eb1,
                        u16* __restrict__ w1b, float* __restrict__ bias2) {
    int i = blockIdx.x * 256 + threadIdx.x;
    if (i >= 3 * H1P * 256) return;
    int k = i & 255;
    int n = (i >> 8) % H1P;
    int l = (i >> 8) / H1P;
    float v = (n < H1) ? ew1[(size_t)l * 257 * H1 + (size_t)k * H1 + n] : 0.f;
    w1b[(size_t)(l * H1P + n) * 256 + k] = f2bf(v);
    if (k == 0) {
        bias2[(l * H1P + n) * 2 + 0] = (n < H1) ? eb1[l * H1 + n] : 0.f;
        bias2[(l * H1P + n) * 2 + 1] = (n < H1) ? ew1[(size_t)l * 257 * H1 + (size_t)256 * H1 + n] : 0.f;
    }
}

// w2b[l][n<64][k<544] (1088B rows)
__global__ void prep_w2(const float* __restrict__ ew2, u16* __restrict__ w2b) {
    int i = blockIdx.x * 256 + threadIdx.x;
    if (i >= 3 * 64 * H1P) return;
    int k = i % H1P;
    int n = (i / H1P) & 63;
    int l = i / (H1P * 64);
    float v = (k < H1) ? ew2[(size_t)l * H1 * 64 + (size_t)k * 64 + n] : 0.f;
    w2b[(size_t)(l * 64 + n) * H1P + k] = f2bf(v);
}

// cw1b[l][n<256][k<64] (128B rows)
__global__ void prep_cw1(const float* __restrict__ cw1, u16* __restrict__ cw1b) {
    int i = blockIdx.x * 256 + threadIdx.x;
    if (i >= 3 * 256 * 64) return;
    int k = i & 63;
    int n = (i >> 6) & 255;
    int l = i >> 14;
    cw1b[(size_t)l * 16384 + n * 64 + k] = f2bf(cw1[(size_t)l * 16384 + k * 256 + n]);
}

// nw1b[l][n<256][k<192] (384B rows)
__global__ void prep_nw1(const float* __restrict__ nw1, u16* __restrict__ nw1b) {
    int i = blockIdx.x * 256 + threadIdx.x;
    if (i >= 3 * 256 * 192) return;
    int k = i % 192;
    int n = (i / 192) & 255;
    int l = i / (192 * 256);
    nw1b[(size_t)(l * 256 + n) * 192 + k] = f2bf(nw1[(size_t)l * 192 * 256 + (size_t)k * 256 + n]);
}

// nw2b[l][n<128][k<256] (512B rows)
__global__ void prep_nw2(const float* __restrict__ nw2, u16* __restrict__ nw2b) {
    int i = blockIdx.x * 256 + threadIdx.x;
    if (i >= 3 * 128 * 256) return;
    int k = i & 255;
    int n = (i >> 8) & 127;
    int l = i >> 15;
    nw2b[(size_t)(l * 128 + n) * 256 + k] = f2bf(nw2[(size_t)l * 256 * 128 + (size_t)k * 128 + n]);
}

// ---------------- fused edge kernel: no barriers, weights direct from L2 ----------------
// 128 edges/block, 4 waves; wave owns 32 edges (2 tiles of 16).
// Swapped MFMA: D[m=weight_col][n=edge] = W(as A) x e_in^T(as B in regs).

__global__ __launch_bounds__(256, 2) void edge_mfma(
    const float* __restrict__ x, const int* __restrict__ eidx,
    const char* __restrict__ w1b, const float* __restrict__ bias2,
    const char* __restrict__ w2b, const float* __restrict__ eb2,
    const char* __restrict__ cw1b, const float* __restrict__ cb1,
    const float* __restrict__ cw2, const float* __restrict__ cb2,
    float* __restrict__ m_i, float* __restrict__ mhat)
{
    __shared__ __align__(16) char LDS[32768];   // 8KB per wave, wave-private
    const int tid = threadIdx.x;
    const int w = tid >> 6, l = tid & 63, lg = l >> 4, lc = l & 15;
    char* WB = LDS + w * 8192;          // staging region (reused later)
    char* HT = WB;                      // [32][72B] hidden-chunk repack
    char* MJ = WB + 2560;               // [32][136B] m_ij repack
    char* CWL = WB + 6912;              // 1KB cw2 copy
    const int ebase = blockIdx.x * 128 + w * 32;

    // ---- per-lane edge metadata (2 edge-tiles) ----
    int dstn[2], srcn[2];
    float rd[2], rcx[2][3];
    #pragma unroll
    for (int et = 0; et < 2; ++et) {
        const int e = ebase + et * 16 + lc;
        const int s = eidx[e];
        const int d = eidx[NE + e];
        srcn[et] = s; dstn[et] = d;
        const float* xs = x + (size_t)s * XD;
        const float* xd = x + (size_t)d * XD;
        const float ax = xs[0] - xd[0], ay = xs[1] - xd[1], az = xs[2] - xd[2];
        rcx[et][0] = ax; rcx[et][1] = ay; rcx[et][2] = az;
        rd[et] = ax * ax + ay * ay + az * az;
    }

    // ---- stage e_in (two halves: p0=feats[dst] k0..127, p1=feats[src] k128..255)
    //      coalesced row copies into XOR-swizzled wave-private LDS, then fragments to regs
    bf16x8 B[2][8];   // [edge-tile][k-tile], held whole MLP1 loop
    #pragma unroll
    for (int p = 0; p < 2; ++p) {
        const int base = __builtin_amdgcn_readfirstlane((p ? 0 : NE) + ebase);
        for (int r = 0; r < 32; ++r) {
            const int nr = eidx[base + r];
            const float a = x[(size_t)nr * XD + 3 + 2 * l];
            const float b = x[(size_t)nr * XD + 4 + 2 * l];
            *(u32*)(WB + r * 256 + ((4 * l) ^ ((r & 15) << 4))) = pk2(a, b);
        }
        LGKM0;   // writes visible to whole wave
        #pragma unroll
        for (int kt = 0; kt < 4; ++kt)
            #pragma unroll
            for (int et = 0; et < 2; ++et)
                B[et][p * 4 + kt] =
                    *(bf16x8*)(WB + (et * 16 + lc) * 256 + ((kt * 64 + lg * 16) ^ (lc << 4)));
        LGKM0;   // reads done before region reuse
    }

    // stage cw2 (256 f32) into wave-private LDS for broadcast reads later
    *(f32x4*)(CWL + l * 16) = *(const f32x4*)(cw2 + l * 4);

    // ---- m_ij accumulators D2[outcol][edge], bias init
    f32x4 c2[4][2];
    #pragma unroll
    for (int ct = 0; ct < 4; ++ct) {
        f32x4 eb = *(const f32x4*)(eb2 + ct * 16 + lg * 4);
        c2[ct][0] = eb; c2[ct][1] = eb;
    }

    const char* pW1 = w1b + lc * 512 + lg * 16;
    const char* pW2 = w2b + lc * 1088 + lg * 16;
    const float* pB = bias2;

    #pragma unroll 1
    for (int ch = 0; ch < NCH; ++ch) {
        // MLP1: two 16-col tiles; A=W1 rows from L2, B=e_in from regs
        #pragma unroll
        for (int nt = 0; nt < 2; ++nt) {
            const float* bp = pB + (nt * 16 + lg * 4) * 2;
            f32x4 q0 = *(const f32x4*)(bp);
            f32x4 q1 = *(const f32x4*)(bp + 4);
            f32x4 c1_0, c1_1;
            c1_0[0] = fmaf(rd[0], q0[1], q0[0]); c1_0[1] = fmaf(rd[0], q0[3], q0[2]);
            c1_0[2] = fmaf(rd[0], q1[1], q1[0]); c1_0[3] = fmaf(rd[0], q1[3], q1[2]);
            c1_1[0] = fmaf(rd[1], q0[1], q0[0]); c1_1[1] = fmaf(rd[1], q0[3], q0[2]);
            c1_1[2] = fmaf(rd[1], q1[1], q1[0]); c1_1[3] = fmaf(rd[1], q1[3], q1[2]);
            #pragma unroll
            for (int kt = 0; kt < 8; ++kt) {
                bf16x8 A = __builtin_bit_cast(bf16x8, *(const u32x4*)(pW1 + nt * 8192 + kt * 64));
                c1_0 = mfma16(A, B[0][kt], c1_0);
                c1_1 = mfma16(A, B[1][kt], c1_1);
            }
            u32x2 v0, v1;
            v0[0] = pk2(silu(c1_0[0]), silu(c1_0[1])); v0[1] = pk2(silu(c1_0[2]), silu(c1_0[3]));
            v1[0] = pk2(silu(c1_1[0]), silu(c1_1[1])); v1[1] = pk2(silu(c1_1[2]), silu(c1_1[3]));
            *(u32x2*)(HT + lc * 72 + nt * 32 + lg * 8) = v0;
            *(u32x2*)(HT + (16 + lc) * 72 + nt * 32 + lg * 8) = v1;
        }
        LGKM0;
        // MLP2 partial accumulate over this 32-wide hidden chunk
        bf16x8 B2[2];
        #pragma unroll
        for (int et = 0; et < 2; ++et) {
            u32x2 a = *(u32x2*)(HT + (et * 16 + lc) * 72 + lg * 16);
            u32x2 b = *(u32x2*)(HT + (et * 16 + lc) * 72 + lg * 16 + 8);
            B2[et] = mk8(a[0], a[1], b[0], b[1]);
        }
        #pragma unroll
        for (int ct = 0; ct < 4; ++ct) {
            bf16x8 A2 = __builtin_bit_cast(bf16x8, *(const u32x4*)(pW2 + ct * 17408));
            c2[ct][0] = mfma16(A2, B2[0], c2[ct][0]);
            c2[ct][1] = mfma16(A2, B2[1], c2[ct][1]);
        }
        LGKM0;
        pW1 += 16384; pW2 += 64; pB += 64;
    }

    // ---- silu -> m_ij: atomic scatter m_i + stash bf16 for coor MLP
    float* mp0 = m_i + (size_t)dstn[0] * 64 + lg * 4;
    float* mp1 = m_i + (size_t)dstn[1] * 64 + lg * 4;
    #pragma unroll
    for (int ct = 0; ct < 4; ++ct) {
        #pragma unroll
        for (int et = 0; et < 2; ++et) {
            f32x4 c = c2[ct][et];
            const float s0 = silu(c[0]), s1 = silu(c[1]), s2 = silu(c[2]), s3 = silu(c[3]);
            u32x2 v; v[0] = pk2(s0, s1); v[1] = pk2(s2, s3);
            *(u32x2*)(MJ + (et * 16 + lc) * 136 + ct * 32 + lg * 8) = v;
            float* mp = et ? mp1 : mp0;
            atomicAdd(mp + ct * 16 + 0, s0);
            atomicAdd(mp + ct * 16 + 1, s1);
            atomicAdd(mp + ct * 16 + 2, s2);
            atomicAdd(mp + ct * 16 + 3, s3);
        }
    }
    LGKM0;

    // ---- coor MLP: D3[cc][edge] = cw1(as A) x m_ij^T(as B); dot with cw2
    bf16x8 B3[2][2];
    #pragma unroll
    for (int et = 0; et < 2; ++et)
        #pragma unroll
        for (int kt = 0; kt < 2; ++kt) {
            u32x2 a = *(u32x2*)(MJ + (et * 16 + lc) * 136 + kt * 64 + lg * 16);
            u32x2 b = *(u32x2*)(MJ + (et * 16 + lc) * 136 + kt * 64 + lg * 16 + 8);
            B3[et][kt] = mk8(a[0], a[1], b[0], b[1]);
        }
    float pw0 = 0.f, pw1 = 0.f;
    #pragma unroll 4
    for (int ct3 = 0; ct3 < 16; ++ct3) {
        f32x4 cb = *(const f32x4*)(cb1 + ct3 * 16 + lg * 4);
        f32x4 c30 = cb, c31 = cb;
        #pragma unroll
        for (int kt = 0; kt < 2; ++kt) {
            bf16x8 A3 = __builtin_bit_cast(bf16x8,
                *(const u32x4*)(cw1b + (ct3 * 16 + lc) * 128 + kt * 64 + lg * 16));
            c30 = mfma16(A3, B3[0][kt], c30);
            c31 = mfma16(A3, B3[1][kt], c31);
        }
        f32x4 wv = *(f32x4*)(CWL + ct3 * 64 + lg * 16);  // broadcast read
        pw0 += silu(c30[0]) * wv[0] + silu(c30[1]) * wv[1] + silu(c30[2]) * wv[2] + silu(c30[3]) * wv[3];
        pw1 += silu(c31[0]) * wv[0] + silu(c31[1]) * wv[1] + silu(c31[2]) * wv[2] + silu(c31[3]) * wv[3];
    }
    pw0 += __shfl_xor(pw0, 16, 64); pw0 += __shfl_xor(pw0, 32, 64);
    pw1 += __shfl_xor(pw1, 16, 64); pw1 += __shfl_xor(pw1, 32, 64);
    const float cb2v = cb2[0];
    const float cwA = pw0 + cb2v, cwB = pw1 + cb2v;
    if (lg < 3) {
        const float rA = (lg == 0) ? rcx[0][0] : ((lg == 1) ? rcx[0][1] : rcx[0][2]);
        const float rB = (lg == 0) ? rcx[1][0] : ((lg == 1) ? rcx[1][1] : rcx[1][2]);
        atomicAdd(mhat + (size_t)dstn[0] * 3 + lg, cwA * rA);
        atomicAdd(mhat + (size_t)dstn[1] * 3 + lg, cwB * rB);
    }
}

// ---------------- node kernel: LN + MLP via MFMA, no barriers ----------------
// 128 nodes/block, 4 waves x 32 nodes. D[m=col][n=node].

__global__ __launch_bounds__(256, 2) void node_mfma(
    const float* __restrict__ xc, const float* __restrict__ m_i, const float* __restrict__ mh,
    const float* __restrict__ ng, const float* __restrict__ nb,
    const char* __restrict__ nw1b, const float* __restrict__ nb1,
    const char* __restrict__ nw2b, const float* __restrict__ nb2,
    float* __restrict__ xn)
{
    __shared__ __align__(16) char LDS[4 * 4352];
    const int tid = threadIdx.x;
    const int w = tid >> 6, l = tid & 63, lg = l >> 4, lc = l & 15;
    char* HB = LDS + w * 4352;
    const int nb0 = blockIdx.x * 128 + w * 32;

    int nodes[2]; bool valid[2];
    #pragma unroll
    for (int et = 0; et < 2; ++et) {
        int n = nb0 + et * 16 + lc;
        valid[et] = (n < NN);
        nodes[et] = valid[et] ? n : (NN - 1);
    }

    // ---- n_in fragments: LN(feats) for k<128, m_i for 128..191
    bf16x8 BF[2][6];
    #pragma unroll
    for (int et = 0; et < 2; ++et) {
        const float* xr = xc + (size_t)nodes[et] * XD + 3;
        float v[4][8];
        float s = 0.f, q = 0.f;
        #pragma unroll
        for (int kt = 0; kt < 4; ++kt) {
            const int k0 = kt * 32 + lg * 8;
            #pragma unroll
            for (int j = 0; j < 8; ++j) {
                const float t = xr[k0 + j];
                v[kt][j] = t; s += t; q = fmaf(t, t, q);
            }
        }
        s += __shfl_xor(s, 16, 64); s += __shfl_xor(s, 32, 64);
        q += __shfl_xor(q, 16, 64); q += __shfl_xor(q, 32, 64);
        const float mu = s * (1.f / 128.f);
        const float rs = rsqrtf(q * (1.f / 128.f) - mu * mu + 1e-5f);
        #pragma unroll
        for (int kt = 0; kt < 4; ++kt) {
            const int k0 = kt * 32 + lg * 8;
            float4 g0 = *(const float4*)(ng + k0), g1 = *(const float4*)(ng + k0 + 4);
            float4 b0 = *(const float4*)(nb + k0), b1 = *(const float4*)(nb + k0 + 4);
            const u32 u0 = pk2((v[kt][0] - mu) * rs * g0.x + b0.x, (v[kt][1] - mu) * rs * g0.y + b0.y);
            const u32 u1 = pk2((v[kt][2] - mu) * rs * g0.z + b0.z, (v[kt][3] - mu) * rs * g0.w + b0.w);
            const u32 u2 = pk2((v[kt][4] - mu) * rs * g1.x + b1.x, (v[kt][5] - mu) * rs * g1.y + b1.y);
            const u32 u3 = pk2((v[kt][6] - mu) * rs * g1.z + b1.z, (v[kt][7] - mu) * rs * g1.w + b1.w);
            BF[et][kt] = mk8(u0, u1, u2, u3);
        }
        const float* mr = m_i + (size_t)nodes[et] * 64;
        #pragma unroll
        for (int kt2 = 0; kt2 < 2; ++kt2) {
            float4 a = *(const float4*)(mr + kt2 * 32 + lg * 8);
            float4 b = *(const float4*)(mr + kt2 * 32 + lg * 8 + 4);
            BF[et][4 + kt2] = mk8(pk2(a.x, a.y), pk2(a.z, a.w), pk2(b.x, b.y), pk2(b.z, b.w));
        }
    }

    // ---- acc2 init (output 128 cols)
    f32x4 a2[8][2];
    #pragma unroll
    for (int ct2 = 0; ct2 < 8; ++ct2) {
        f32x4 b = *(const f32x4*)(nb2 + ct2 * 16 + lg * 4);
        a2[ct2][0] = b; a2[ct2][1] = b;
    }

    // ---- 4 col-groups of 64 hidden: MLP1 -> silu -> repack -> MLP2 accumulate
    #pragma unroll 1
    for (int g = 0; g < 4; ++g) {
        f32x4 a1[4][2];
        #pragma unroll
        for (int ct = 0; ct < 4; ++ct) {
            f32x4 b = *(const f32x4*)(nb1 + g * 64 + ct * 16 + lg * 4);
            a1[ct][0] = b; a1[ct][1] = b;
        }
        #pragma unroll
        for (int ct = 0; ct < 4; ++ct)
            #pragma unroll
            for (int kt = 0; kt < 6; ++kt) {
                bf16x8 A = __builtin_bit_cast(bf16x8, *(const u32x4*)(
                    nw1b + (size_t)(g * 64 + ct * 16 + lc) * 384 + kt * 64 + lg * 16));
                a1[ct][0] = mfma16(A, BF[0][kt], a1[ct][0]);
                a1[ct][1] = mfma16(A, BF[1][kt], a1[ct][1]);
            }
        #pragma unroll
        for (int ct = 0; ct < 4; ++ct)
            #pragma unroll
            for (int et = 0; et < 2; ++et) {
                f32x4 c = a1[ct][et];
                u32x2 v;
                v[0] = pk2(silu(c[0]), silu(c[1]));
                v[1] = pk2(silu(c[2]), silu(c[3]));
                *(u32x2*)(HB + (et * 16 + lc) * 136 + ct * 32 + lg * 8) = v;
            }
        LGKM0;
        bf16x8 B2[2][2];
        #pragma unroll
        for (int et = 0; et < 2; ++et)
            #pragma unroll
            for (int kt2 = 0; kt2 < 2; ++kt2) {
                u32x2 a = *(u32x2*)(HB + (et * 16 + lc) * 136 + kt2 * 64 + lg * 16);
                u32x2 b = *(u32x2*)(HB + (et * 16 + lc) * 136 + kt2 * 64 + lg * 16 + 8);
                B2[et][kt2] = mk8(a[0], a[1], b[0], b[1]);
            }
        #pragma unroll
        for (int ct2 = 0; ct2 < 8; ++ct2)
            #pragma unroll
            for (int kt2 = 0; kt2 < 2; ++kt2) {
                bf16x8 A2 = __builtin_bit_cast(bf16x8, *(const u32x4*)(
                    nw2b + (size_t)(ct2 * 16 + lc) * 512 + (g * 64 + kt2 * 32 + lg * 8) * 2));
                a2[ct2][0] = mfma16(A2, B2[0][kt2], a2[ct2][0]);
                a2[ct2][1] = mfma16(A2, B2[1][kt2], a2[ct2][1]);
            }
        LGKM0;
    }

    // ---- epilogue: residual add, write feats
    #pragma unroll
    for (int et = 0; et < 2; ++et) {
        if (!valid[et]) continue;
        const size_t nr = (size_t)nodes[et] * XD;
        #pragma unroll
        for (int ct2 = 0; ct2 < 8; ++ct2) {
            #pragma unroll
            for (int r = 0; r < 4; ++r) {
                const int col = ct2 * 16 + lg * 4 + r;
                xn[nr + 3 + col] = a2[ct2][et][r] + xc[nr + 3 + col];
            }
        }
    }
    // coors update
    for (int idx = tid; idx < 384; idx += 256) {
        const int n = blockIdx.x * 128 + idx / 3;
        const int d = idx - (idx / 3) * 3;
        if (n < NN)
            xn[(size_t)n * XD + d] = xc[(size_t)n * XD + d] + mh[n * 3 + d];
    }
}

// ---------------- launch ----------------

extern "C" void kernel_launch(void* const* d_in, const int* in_sizes, int n_in,
                              void* d_out, int out_size, void* d_ws, size_t ws_size,
                              hipStream_t stream) {
    const float* x_in = (const float*)d_in[0];
    const int*   eidx = (const int*)  d_in[1];
    const float* ew1  = (const float*)d_in[2];
    const float* eb1  = (const float*)d_in[3];
    const float* ew2  = (const float*)d_in[4];
    const float* eb2  = (const float*)d_in[5];
    const float* ng   = (const float*)d_in[6];
    const float* nb   = (const float*)d_in[7];
    const float* nw1  = (const float*)d_in[8];
    const float* nb1  = (const float*)d_in[9];
    const float* nw2  = (const float*)d_in[10];
    const float* nb2  = (const float*)d_in[11];
    const float* cw1  = (const float*)d_in[12];
    const float* cb1  = (const float*)d_in[13];
    const float* cw2  = (const float*)d_in[14];
    const float* cb2  = (const float*)d_in[15];
    float* out = (float*)d_out;

    char* ws = (char*)d_ws;
    size_t off = 0;
    auto alloc = [&](size_t bytes) { char* p = ws + off; off = (off + bytes + 255) & ~255ull; return p; };
    float* xA    = (float*)alloc((size_t)NN * XD * 4);
    float* mi    = (float*)alloc((size_t)NN * 64 * 4);
    float* mh    = (float*)alloc((size_t)NN * 3 * 4);
    float* bias2 = (float*)alloc((size_t)3 * H1P * 8);
    char*  w1b   = alloc((size_t)3 * H1P * 512);
    char*  w2b   = alloc((size_t)3 * 64 * 1088);
    char*  cw1b  = alloc((size_t)3 * 256 * 128);
    char*  nw1b  = alloc((size_t)3 * 256 * 384);
    char*  nw2b  = alloc((size_t)3 * 128 * 512);

    prep_w1 <<<(3 * H1P * 256 + 255) / 256, 256, 0, stream>>>(ew1, eb1, (u16*)w1b, bias2);
    prep_w2 <<<(3 * 64 * H1P + 255) / 256, 256, 0, stream>>>(ew2, (u16*)w2b);
    prep_cw1<<<(3 * 256 * 64 + 255) / 256, 256, 0, stream>>>(cw1, (u16*)cw1b);
    prep_nw1<<<(3 * 256 * 192 + 255) / 256, 256, 0, stream>>>(nw1, (u16*)nw1b);
    prep_nw2<<<(3 * 128 * 256 + 255) / 256, 256, 0, stream>>>(nw2, (u16*)nw2b);

    for (int l = 0; l < 3; ++l) {
        const float* xc = (l == 0) ? x_in : ((l == 1) ? xA : out);
        float*       xn = (l == 0) ? xA : out;
        hipMemsetAsync(mi, 0, (size_t)NN * 64 * 4, stream);
        hipMemsetAsync(mh, 0, (size_t)NN * 3 * 4, stream);
        edge_mfma<<<NE / 128, 256, 0, stream>>>(
            xc, eidx,
            w1b + (size_t)l * H1P * 512, bias2 + (size_t)l * H1P * 2,
            w2b + (size_t)l * 64 * 1088, eb2 + (size_t)l * 64,
            cw1b + (size_t)l * 256 * 128, cb1 + (size_t)l * 256,
            cw2 + (size_t)l * 256, cb2 + l,
            mi, mh);
        node_mfma<<<(NN + 127) / 128, 256, 0, stream>>>(
            xc, mi, mh,
            ng + (size_t)l * 128, nb + (size_t)l * 128,
            nw1b + (size_t)l * 256 * 384, nb1 + (size_t)l * 256,
            nw2b + (size_t)l * 128 * 512, nb2 + (size_t)l * 128,
            xn);
    }
}

// Round 7
// 1091.254 us; speedup vs baseline: 2.0681x; 2.0681x over previous
//
#include <hip/hip_runtime.h>

typedef unsigned short u16;
typedef unsigned int   u32;
typedef __attribute__((ext_vector_type(4))) u32  u32x4;
typedef __attribute__((ext_vector_type(8))) __bf16 bf16x8;
typedef __attribute__((ext_vector_type(4))) float  f32x4;

#define NN 20000
#define NE 320000
#define XD 131
#define F  128
#define MD 64
#define H1 514
#define H1P 544
#define NCH 17

#define GAS __attribute__((address_space(1)))
#define LAS __attribute__((address_space(3)))
#define LGKM0 asm volatile("s_waitcnt lgkmcnt(0)" ::: "memory")

__device__ __forceinline__ float silu(float a) { return a / (1.0f + __expf(-a)); }

__device__ __forceinline__ u16 f2bf(float f) {   // fp32 -> bf16 RNE
    u32 u = __builtin_bit_cast(u32, f);
    return (u16)((u + 0x7FFFu + ((u >> 16) & 1u)) >> 16);
}
__device__ __forceinline__ u32 pk2(float a, float b) {
    return (u32)__builtin_bit_cast(u16, (__bf16)a) |
           ((u32)__builtin_bit_cast(u16, (__bf16)b) << 16);
}
__device__ __forceinline__ bf16x8 mk8(u32 a, u32 b, u32 c, u32 d) {
    u32x4 t = {a, b, c, d};
    return __builtin_bit_cast(bf16x8, t);
}
__device__ __forceinline__ f32x4 mfma16(bf16x8 a, bf16x8 b, f32x4 c) {
    return __builtin_amdgcn_mfma_f32_16x16x32_bf16(a, b, c, 0, 0, 0);
}

// ---------------- weight prep kernels ----------------

// w1T[l][n<544][k<256], XOR-swizzled within each 512B row: elem k at k ^ ((n&7)<<3)
__global__ void prep_w1(const float* __restrict__ ew1, const float* __restrict__ eb1,
                        u16* __restrict__ w1T, float* __restrict__ w1l, float* __restrict__ eb1p) {
    int i = blockIdx.x * 256 + threadIdx.x;
    if (i >= 3 * H1P * 256) return;
    int k = i & 255;
    int n = (i >> 8) % H1P;
    int l = (i >> 8) / H1P;
    float v = (n < H1) ? ew1[(size_t)l * 257 * H1 + (size_t)k * H1 + n] : 0.f;
    w1T[(size_t)l * H1P * 256 + (size_t)n * 256 + (k ^ ((n & 7) << 3))] = f2bf(v);
    if (k == 0) {
        w1l[l * H1P + n]  = (n < H1) ? ew1[(size_t)l * 257 * H1 + (size_t)256 * H1 + n] : 0.f;
        eb1p[l * H1P + n] = (n < H1) ? eb1[l * H1 + n] : 0.f;
    }
}

// w2T[l][n<64][k<544]
__global__ void prep_w2(const float* __restrict__ ew2, u16* __restrict__ w2T) {
    int i = blockIdx.x * 256 + threadIdx.x;
    if (i >= 3 * 64 * H1P) return;
    int k = i % H1P;
    int n = (i / H1P) & 63;
    int l = i / (H1P * 64);
    float v = (k < H1) ? ew2[(size_t)l * H1 * 64 + (size_t)k * 64 + n] : 0.f;
    w2T[(size_t)l * 64 * H1P + (size_t)n * H1P + k] = f2bf(v);
}

// cw1T[l][n<256][k<64]
__global__ void prep_cw1(const float* __restrict__ cw1, u16* __restrict__ cw1T) {
    int i = blockIdx.x * 256 + threadIdx.x;
    if (i >= 3 * 256 * 64) return;
    int k = i & 63;
    int n = (i >> 6) & 255;
    int l = i >> 14;
    cw1T[(size_t)l * 16384 + n * 64 + k] = f2bf(cw1[(size_t)l * 16384 + k * 256 + n]);
}

// nw1b[l][n<256][k<192]
__global__ void prep_nw1(const float* __restrict__ nw1, u16* __restrict__ nw1b) {
    int i = blockIdx.x * 256 + threadIdx.x;
    if (i >= 3 * 256 * 192) return;
    int k = i % 192;
    int n = (i / 192) & 255;
    int l = i / (192 * 256);
    nw1b[(size_t)(l * 256 + n) * 192 + k] = f2bf(nw1[(size_t)l * 192 * 256 + (size_t)k * 256 + n]);
}

// nw2b[l][n<128][k<256]
__global__ void prep_nw2(const float* __restrict__ nw2, u16* __restrict__ nw2b) {
    int i = blockIdx.x * 256 + threadIdx.x;
    if (i >= 3 * 128 * 256) return;
    int k = i & 255;
    int n = (i >> 8) & 127;
    int l = i >> 15;
    nw2b[(size_t)(l * 128 + n) * 256 + k] = f2bf(nw2[(size_t)l * 256 * 128 + (size_t)k * 128 + n]);
}

// feats fp32 -> bf16 copy: xbf[node][128] (stored as u32 pairs; NN*64 u32 = NN*256 BYTES)
__global__ void x2bf(const float* __restrict__ xc, u32* __restrict__ xbf) {
    int i = blockIdx.x * 256 + threadIdx.x;   // NN*64
    if (i >= NN * 64) return;
    const int node = i >> 6, p = i & 63;
    const float a = xc[(size_t)node * XD + 3 + 2 * p];
    const float b = xc[(size_t)node * XD + 4 + 2 * p];
    xbf[(size_t)node * 64 + p] = pk2(a, b);
}

// ---------------- fused edge kernel (round-2 structure + waitcnt-correct staging) ----------------
// 128 edges/block, 4 waves; wave w owns edges [w*32, w*32+32)

__global__ __launch_bounds__(256, 3) void edge_mfma(
    const float* __restrict__ x, const u16* __restrict__ xbf, const int* __restrict__ eidx,
    const u16* __restrict__ w1T, const float* __restrict__ w1l, const float* __restrict__ eb1p,
    const u16* __restrict__ w2T, const float* __restrict__ eb2,
    const u16* __restrict__ cw1T, const float* __restrict__ cb1,
    const float* __restrict__ cw2, const float* __restrict__ cb2,
    float* __restrict__ m_i, float* __restrict__ mhat)
{
    __shared__ __align__(16) char U[34816];   // union: ein-phase | B1+Hc | mij
    __shared__ float rcx[128][4];             // rel_coors xyz + rel_dist
    __shared__ int   sdst[128];

    char* B1 = U;            // 32 x 512B  (16KB)  W1 chunk, swizzled
    char* Hc = U + 16384;    // 128 x 112B (14KB)  h chunk bf16, 56-elem rows

    const int tid = threadIdx.x;
    const int w   = tid >> 6;
    const int l   = tid & 63;
    const int lg  = l >> 4;      // k-group 0..3
    const int lc  = l & 15;      // col/row within 16-tile
    const int e0  = blockIdx.x * 128;

    if (tid < 128) {
        const int s = eidx[e0 + tid];
        const int d = eidx[NE + e0 + tid];
        float ax = x[(size_t)s*XD+0] - x[(size_t)d*XD+0];
        float ay = x[(size_t)s*XD+1] - x[(size_t)d*XD+1];
        float az = x[(size_t)s*XD+2] - x[(size_t)d*XD+2];
        rcx[tid][0] = ax; rcx[tid][1] = ay; rcx[tid][2] = az;
        rcx[tid][3] = ax*ax + ay*ay + az*az;
        sdst[tid] = d;
    }

    // ---- stage e_in in two phases (p0: feats[dst] k0..127, p1: feats[src] k128..255)
    //      vector copies from bf16 source; fragment reads DRAINED before region reuse
    bf16x8 A[2][8];   // [mt][kt]
    #pragma unroll
    for (int p = 0; p < 2; ++p) {
        __syncthreads();
        {
            const int el = tid >> 1;             // edge-in-block 0..127 (wave-private rows)
            const int cb = (tid & 1) << 6;       // u16 col base 0/64
            const int node = eidx[(p == 0 ? NE : 0) + e0 + el];
            const u16* src = xbf + (size_t)node * 128 + cb;
            char* dst = U + el * 272 + cb * 2;
            #pragma unroll
            for (int i = 0; i < 8; ++i)
                *(u32x4*)(dst + i * 16) = *(const u32x4*)(src + i * 8);
        }
        __syncthreads();
        #pragma unroll
        for (int kt = 0; kt < 4; ++kt)
            #pragma unroll
            for (int mt = 0; mt < 2; ++mt) {
                const int row = w * 32 + mt * 16 + lc;
                A[mt][p * 4 + kt] = *(bf16x8*)(U + row * 272 + kt * 64 + lg * 16);
            }
        // Drain the fragment ds_reads NOW: the next phase / chunk-0 global_load_lds
        // overwrites this region, and s_barrier does NOT wait on lgkmcnt.
        LGKM0;
        __builtin_amdgcn_sched_barrier(0);
    }
    __syncthreads();   // einS region dead; B1/Hc may be written

    // ---- m_ij accumulators (M=32 per wave, N=64), bias init
    f32x4 c2[2][4];
    #pragma unroll
    for (int nt = 0; nt < 4; ++nt) {
        const float b = eb2[nt * 16 + lc];
        #pragma unroll
        for (int mt = 0; mt < 2; ++mt) c2[mt][nt] = (f32x4){b, b, b, b};
    }

    // ---- chunk loop over H1P (17 x 32 cols): MLP1 -> silu -> MLP2-accumulate
    for (int ch = 0; ch < NCH; ++ch) {
        // stage W1 chunk (pre-swizzled in global) -> LDS, 16KB, 4KB per wave
        {
            const char* gsrc = (const char*)(w1T + (size_t)ch * 32 * 256);
            #pragma unroll
            for (int r = 0; r < 4; ++r) {
                const int off = (w * 4 + r) * 1024;
                __builtin_amdgcn_global_load_lds((const GAS u32*)(gsrc + off + l * 16),
                                                 (LAS u32*)(B1 + off), 16, 0, 0);
            }
        }
        asm volatile("s_waitcnt vmcnt(0)" ::: "memory");
        __syncthreads();

        // MLP1: two 16-col tiles
        #pragma unroll
        for (int nt = 0; nt < 2; ++nt) {
            const int col = ch * 32 + nt * 16 + lc;
            const float bias = eb1p[col];
            const float wl   = w1l[col];
            f32x4 c1[2];
            #pragma unroll
            for (int mt = 0; mt < 2; ++mt)
                #pragma unroll
                for (int r = 0; r < 4; ++r)
                    c1[mt][r] = fmaf(rcx[w * 32 + mt * 16 + lg * 4 + r][3], wl, bias);
            #pragma unroll
            for (int kt = 0; kt < 8; ++kt) {
                const int nl = nt * 16 + lc;
                const int kb = (kt * 64 + lg * 16) ^ ((nl & 7) << 4);
                bf16x8 B = *(bf16x8*)(B1 + nl * 512 + kb);
                c1[0] = mfma16(A[0][kt], B, c1[0]);
                c1[1] = mfma16(A[1][kt], B, c1[1]);
            }
            #pragma unroll
            for (int mt = 0; mt < 2; ++mt)
                #pragma unroll
                for (int r = 0; r < 4; ++r) {
                    const int row = w * 32 + mt * 16 + lg * 4 + r;
                    ((u16*)Hc)[row * 56 + nt * 16 + lc] = f2bf(silu(c1[mt][r]));
                }
        }
        // MLP2 partial accumulate (A from Hc — wave-local rows, B from global L2)
        bf16x8 A2[2];
        #pragma unroll
        for (int mt = 0; mt < 2; ++mt)
            A2[mt] = *(bf16x8*)(Hc + (w * 32 + mt * 16 + lc) * 112 + lg * 16);
        #pragma unroll
        for (int nt = 0; nt < 4; ++nt) {
            bf16x8 B = *(const bf16x8*)(w2T + (size_t)(nt * 16 + lc) * H1P + ch * 32 + lg * 8);
            c2[0][nt] = mfma16(A2[0], B, c2[0][nt]);
            c2[1][nt] = mfma16(A2[1], B, c2[1][nt]);
        }
        __syncthreads();   // all B1/Hc reads consumed by MFMAs above before next stage
    }

    // ---- silu -> m_ij: scatter-add m_i, stash bf16 m_ij in LDS (wave-local rows)
    u16* mijL = (u16*)U;   // 128 x 72 elems (144B rows)
    #pragma unroll
    for (int mt = 0; mt < 2; ++mt)
        #pragma unroll
        for (int nt = 0; nt < 4; ++nt)
            #pragma unroll
            for (int r = 0; r < 4; ++r) {
                const float v = silu(c2[mt][nt][r]);
                const int rowl = w * 32 + mt * 16 + lg * 4 + r;
                const int col  = nt * 16 + lc;
                mijL[rowl * 72 + col] = f2bf(v);
                atomicAdd(&m_i[(size_t)sdst[rowl] * MD + col], v);
            }

    // ---- coor MLP: silu(m_ij @ cw1 + cb1) @ cw2 + cb2 (B direct from L2)
    bf16x8 A3[2][2];
    #pragma unroll
    for (int mt = 0; mt < 2; ++mt)
        #pragma unroll
        for (int kt = 0; kt < 2; ++kt)
            A3[mt][kt] = *(bf16x8*)(U + (w * 32 + mt * 16 + lc) * 144 + kt * 64 + lg * 16);

    float pw[2][4] = {{0.f,0.f,0.f,0.f},{0.f,0.f,0.f,0.f}};
    #pragma unroll 4
    for (int nt = 0; nt < 16; ++nt) {
        const int col = nt * 16 + lc;
        const float b = cb1[col];
        f32x4 c3[2];
        #pragma unroll
        for (int mt = 0; mt < 2; ++mt) c3[mt] = (f32x4){b, b, b, b};
        #pragma unroll
        for (int kt = 0; kt < 2; ++kt) {
            bf16x8 B = *(const bf16x8*)(cw1T + (size_t)col * 64 + kt * 32 + lg * 8);
            c3[0] = mfma16(A3[0][kt], B, c3[0]);
            c3[1] = mfma16(A3[1][kt], B, c3[1]);
        }
        const float w2v = cw2[col];
        #pragma unroll
        for (int mt = 0; mt < 2; ++mt)
            #pragma unroll
            for (int r = 0; r < 4; ++r)
                pw[mt][r] = fmaf(silu(c3[mt][r]), w2v, pw[mt][r]);
    }
    #pragma unroll
    for (int m = 1; m < 16; m <<= 1)
        #pragma unroll
        for (int mt = 0; mt < 2; ++mt)
            #pragma unroll
            for (int r = 0; r < 4; ++r)
                pw[mt][r] += __shfl_xor(pw[mt][r], m, 16);

    const float cb2v = cb2[0];
    if (lc < 3) {
        #pragma unroll
        for (int mt = 0; mt < 2; ++mt)
            #pragma unroll
            for (int r = 0; r < 4; ++r) {
                const int rowl = w * 32 + mt * 16 + lg * 4 + r;
                const float cw = pw[mt][r] + cb2v;
                atomicAdd(&mhat[(size_t)sdst[rowl] * 3 + lc], cw * rcx[rowl][lc]);
            }
    }
}

// ---------------- node kernel: LN + MLP via MFMA ----------------

__global__ __launch_bounds__(256, 2) void node_mfma(
    const float* __restrict__ xc, const float* __restrict__ m_i, const float* __restrict__ mh,
    const float* __restrict__ ng, const float* __restrict__ nb,
    const char* __restrict__ nw1b, const float* __restrict__ nb1,
    const char* __restrict__ nw2b, const float* __restrict__ nb2,
    float* __restrict__ xn)
{
    __shared__ __align__(16) char LDS[4 * 4352];
    const int tid = threadIdx.x;
    const int w = tid >> 6, l = tid & 63, lg = l >> 4, lc = l & 15;
    char* HB = LDS + w * 4352;
    const int nb0 = blockIdx.x * 128 + w * 32;

    int nodes[2]; bool valid[2];
    #pragma unroll
    for (int et = 0; et < 2; ++et) {
        int n = nb0 + et * 16 + lc;
        valid[et] = (n < NN);
        nodes[et] = valid[et] ? n : (NN - 1);
    }

    bf16x8 BF[2][6];
    #pragma unroll
    for (int et = 0; et < 2; ++et) {
        const float* xr = xc + (size_t)nodes[et] * XD + 3;
        float v[4][8];
        float s = 0.f, q = 0.f;
        #pragma unroll
        for (int kt = 0; kt < 4; ++kt) {
            const int k0 = kt * 32 + lg * 8;
            #pragma unroll
            for (int j = 0; j < 8; ++j) {
                const float t = xr[k0 + j];
                v[kt][j] = t; s += t; q = fmaf(t, t, q);
            }
        }
        s += __shfl_xor(s, 16, 64); s += __shfl_xor(s, 32, 64);
        q += __shfl_xor(q, 16, 64); q += __shfl_xor(q, 32, 64);
        const float mu = s * (1.f / 128.f);
        const float rs = rsqrtf(q * (1.f / 128.f) - mu * mu + 1e-5f);
        #pragma unroll
        for (int kt = 0; kt < 4; ++kt) {
            const int k0 = kt * 32 + lg * 8;
            float4 g0 = *(const float4*)(ng + k0), g1 = *(const float4*)(ng + k0 + 4);
            float4 b0 = *(const float4*)(nb + k0), b1 = *(const float4*)(nb + k0 + 4);
            const u32 u0 = pk2((v[kt][0] - mu) * rs * g0.x + b0.x, (v[kt][1] - mu) * rs * g0.y + b0.y);
            const u32 u1 = pk2((v[kt][2] - mu) * rs * g0.z + b0.z, (v[kt][3] - mu) * rs * g0.w + b0.w);
            const u32 u2 = pk2((v[kt][4] - mu) * rs * g1.x + b1.x, (v[kt][5] - mu) * rs * g1.y + b1.y);
            const u32 u3 = pk2((v[kt][6] - mu) * rs * g1.z + b1.z, (v[kt][7] - mu) * rs * g1.w + b1.w);
            BF[et][kt] = mk8(u0, u1, u2, u3);
        }
        const float* mr = m_i + (size_t)nodes[et] * 64;
        #pragma unroll
        for (int kt2 = 0; kt2 < 2; ++kt2) {
            float4 a = *(const float4*)(mr + kt2 * 32 + lg * 8);
            float4 b = *(const float4*)(mr + kt2 * 32 + lg * 8 + 4);
            BF[et][4 + kt2] = mk8(pk2(a.x, a.y), pk2(a.z, a.w), pk2(b.x, b.y), pk2(b.z, b.w));
        }
    }

    f32x4 a2[8][2];
    #pragma unroll
    for (int ct2 = 0; ct2 < 8; ++ct2) {
        f32x4 b = *(const f32x4*)(nb2 + ct2 * 16 + lg * 4);
        a2[ct2][0] = b; a2[ct2][1] = b;
    }

    #pragma unroll 1
    for (int g = 0; g < 4; ++g) {
        f32x4 a1[4][2];
        #pragma unroll
        for (int ct = 0; ct < 4; ++ct) {
            f32x4 b = *(const f32x4*)(nb1 + g * 64 + ct * 16 + lg * 4);
            a1[ct][0] = b; a1[ct][1] = b;
        }
        #pragma unroll
        for (int ct = 0; ct < 4; ++ct)
            #pragma unroll
            for (int kt = 0; kt < 6; ++kt) {
                bf16x8 Aw = __builtin_bit_cast(bf16x8, *(const u32x4*)(
                    nw1b + (size_t)(g * 64 + ct * 16 + lc) * 384 + kt * 64 + lg * 16));
                a1[ct][0] = mfma16(Aw, BF[0][kt], a1[ct][0]);
                a1[ct][1] = mfma16(Aw, BF[1][kt], a1[ct][1]);
            }
        #pragma unroll
        for (int ct = 0; ct < 4; ++ct)
            #pragma unroll
            for (int et = 0; et < 2; ++et) {
                f32x4 c = a1[ct][et];
                u32 v0 = pk2(silu(c[0]), silu(c[1]));
                u32 v1 = pk2(silu(c[2]), silu(c[3]));
                *(u32*)(HB + (et * 16 + lc) * 136 + ct * 32 + lg * 8) = v0;
                *(u32*)(HB + (et * 16 + lc) * 136 + ct * 32 + lg * 8 + 4) = v1;
            }
        LGKM0;
        __builtin_amdgcn_sched_barrier(0);
        bf16x8 B2[2][2];
        #pragma unroll
        for (int et = 0; et < 2; ++et)
            #pragma unroll
            for (int kt2 = 0; kt2 < 2; ++kt2) {
                u32 a = *(u32*)(HB + (et * 16 + lc) * 136 + kt2 * 64 + lg * 16);
                u32 b = *(u32*)(HB + (et * 16 + lc) * 136 + kt2 * 64 + lg * 16 + 4);
                u32 c = *(u32*)(HB + (et * 16 + lc) * 136 + kt2 * 64 + lg * 16 + 8);
                u32 d = *(u32*)(HB + (et * 16 + lc) * 136 + kt2 * 64 + lg * 16 + 12);
                B2[et][kt2] = mk8(a, b, c, d);
            }
        #pragma unroll
        for (int ct2 = 0; ct2 < 8; ++ct2)
            #pragma unroll
            for (int kt2 = 0; kt2 < 2; ++kt2) {
                bf16x8 Aw = __builtin_bit_cast(bf16x8, *(const u32x4*)(
                    nw2b + (size_t)(ct2 * 16 + lc) * 512 + (g * 64 + kt2 * 32 + lg * 8) * 2));
                a2[ct2][0] = mfma16(Aw, B2[0][kt2], a2[ct2][0]);
                a2[ct2][1] = mfma16(Aw, B2[1][kt2], a2[ct2][1]);
            }
        LGKM0;
        __builtin_amdgcn_sched_barrier(0);
    }

    #pragma unroll
    for (int et = 0; et < 2; ++et) {
        if (!valid[et]) continue;
        const size_t nr = (size_t)nodes[et] * XD;
        #pragma unroll
        for (int ct2 = 0; ct2 < 8; ++ct2)
            #pragma unroll
            for (int r = 0; r < 4; ++r) {
                const int col = ct2 * 16 + lg * 4 + r;
                xn[nr + 3 + col] = a2[ct2][et][r] + xc[nr + 3 + col];
            }
    }
    for (int idx = tid; idx < 384; idx += 256) {
        const int n = blockIdx.x * 128 + idx / 3;
        const int d = idx - (idx / 3) * 3;
        if (n < NN)
            xn[(size_t)n * XD + d] = xc[(size_t)n * XD + d] + mh[n * 3 + d];
    }
}

// ---------------- launch ----------------

extern "C" void kernel_launch(void* const* d_in, const int* in_sizes, int n_in,
                              void* d_out, int out_size, void* d_ws, size_t ws_size,
                              hipStream_t stream) {
    const float* x_in = (const float*)d_in[0];
    const int*   eidx = (const int*)  d_in[1];
    const float* ew1  = (const float*)d_in[2];
    const float* eb1  = (const float*)d_in[3];
    const float* ew2  = (const float*)d_in[4];
    const float* eb2  = (const float*)d_in[5];
    const float* ng   = (const float*)d_in[6];
    const float* nb   = (const float*)d_in[7];
    const float* nw1  = (const float*)d_in[8];
    const float* nb1  = (const float*)d_in[9];
    const float* nw2  = (const float*)d_in[10];
    const float* nb2  = (const float*)d_in[11];
    const float* cw1  = (const float*)d_in[12];
    const float* cb1  = (const float*)d_in[13];
    const float* cw2  = (const float*)d_in[14];
    const float* cb2  = (const float*)d_in[15];
    float* out = (float*)d_out;

    char* ws = (char*)d_ws;
    size_t off = 0;
    auto alloc = [&](size_t bytes) { char* p = ws + off; off = (off + bytes + 255) & ~255ull; return p; };
    float* mi    = (float*)alloc((size_t)NN * MD * 4);
    float* mh    = (float*)alloc((size_t)NN * 3 * 4);
    u32*   xbf   = (u32*)  alloc((size_t)NN * 256);   // NN*64 u32 = NN*256 BYTES (was NN*128: overflow clobbered weights -> NaN)
    float* w1l   = (float*)alloc((size_t)3 * H1P * 4);
    float* eb1p  = (float*)alloc((size_t)3 * H1P * 4);
    u16*   w1T   = (u16*)  alloc((size_t)3 * H1P * 512);
    u16*   w2T   = (u16*)  alloc((size_t)3 * 64 * H1P * 2);
    u16*   cw1T  = (u16*)  alloc((size_t)3 * 256 * 128);
    char*  nw1b  =         alloc((size_t)3 * 256 * 384);
    char*  nw2b  =         alloc((size_t)3 * 128 * 512);

    prep_w1 <<<(3 * H1P * 256 + 255) / 256, 256, 0, stream>>>(ew1, eb1, w1T, w1l, eb1p);
    prep_w2 <<<(3 * 64 * H1P + 255) / 256, 256, 0, stream>>>(ew2, w2T);
    prep_cw1<<<(3 * 256 * 64 + 255) / 256, 256, 0, stream>>>(cw1, cw1T);
    prep_nw1<<<(3 * 256 * 192 + 255) / 256, 256, 0, stream>>>(nw1, (u16*)nw1b);
    prep_nw2<<<(3 * 128 * 256 + 255) / 256, 256, 0, stream>>>(nw2, (u16*)nw2b);

    for (int l = 0; l < 3; ++l) {
        // layer I/O: l0 reads x_in, writes d_out; l1/l2 update d_out in place
        // (safe: node_mfma threads read their own node's data before writing it)
        const float* xc = (l == 0) ? x_in : out;
        float*       xn = out;
        hipMemsetAsync(mi, 0, (size_t)NN * MD * 4, stream);
        hipMemsetAsync(mh, 0, (size_t)NN * 3 * 4, stream);
        x2bf<<<(NN * 64 + 255) / 256, 256, 0, stream>>>(xc, xbf);
        edge_mfma<<<NE / 128, 256, 0, stream>>>(
            xc, (const u16*)xbf, eidx,
            w1T + (size_t)l * H1P * 256, w1l + (size_t)l * H1P, eb1p + (size_t)l * H1P,
            w2T + (size_t)l * 64 * H1P, eb2 + (size_t)l * 64,
            cw1T + (size_t)l * 256 * 64, cb1 + (size_t)l * 256,
            cw2 + (size_t)l * 256, cb2 + l,
            mi, mh);
        node_mfma<<<(NN + 127) / 128, 256, 0, stream>>>(
            xc, mi, mh,
            ng + (size_t)l * F, nb + (size_t)l * F,
            nw1b + (size_t)l * 256 * 384, nb1 + (size_t)l * 256,
            nw2b + (size_t)l * 128 * 512, nb2 + (size_t)l * F,
            xn);
    }
}

// Round 8
// 1064.881 us; speedup vs baseline: 2.1193x; 1.0248x over previous
//
#include <hip/hip_runtime.h>

typedef unsigned short u16;
typedef unsigned int   u32;
typedef __attribute__((ext_vector_type(4))) u32  u32x4;
typedef __attribute__((ext_vector_type(8))) __bf16 bf16x8;
typedef __attribute__((ext_vector_type(4))) float  f32x4;

#define NN 20000
#define NE 320000
#define XD 131
#define F  128
#define MD 64
#define H1 514
#define H1P 544
#define NCH 17

#define GAS __attribute__((address_space(1)))
#define LAS __attribute__((address_space(3)))
#define LGKM0 asm volatile("s_waitcnt lgkmcnt(0)" ::: "memory")
#define VM0   asm volatile("s_waitcnt vmcnt(0)" ::: "memory")

__device__ __forceinline__ float silu(float a) { return a / (1.0f + __expf(-a)); }

__device__ __forceinline__ u16 f2bf(float f) {   // fp32 -> bf16 RNE
    u32 u = __builtin_bit_cast(u32, f);
    return (u16)((u + 0x7FFFu + ((u >> 16) & 1u)) >> 16);
}
__device__ __forceinline__ u16 bfc(float f) { return __builtin_bit_cast(u16, (__bf16)f); }
__device__ __forceinline__ u32 pk2(float a, float b) {
    return (u32)bfc(a) | ((u32)bfc(b) << 16);
}
__device__ __forceinline__ bf16x8 mk8(u32 a, u32 b, u32 c, u32 d) {
    u32x4 t = {a, b, c, d};
    return __builtin_bit_cast(bf16x8, t);
}
__device__ __forceinline__ f32x4 mfma16(bf16x8 a, bf16x8 b, f32x4 c) {
    return __builtin_amdgcn_mfma_f32_16x16x32_bf16(a, b, c, 0, 0, 0);
}

// ---------------- weight prep ----------------

// w1b[l][n<544][k<256] 512B rows, elem k stored at k ^ ((n&7)<<3)  (XOR pre-swizzle)
// bias2[l][n] = {eb1[n], w1_row256[n]}
__global__ void prep_w1(const float* __restrict__ ew1, const float* __restrict__ eb1,
                        u16* __restrict__ w1b, float* __restrict__ bias2) {
    int i = blockIdx.x * 256 + threadIdx.x;
    if (i >= 3 * H1P * 256) return;
    int k = i & 255;
    int n = (i >> 8) % H1P;
    int l = (i >> 8) / H1P;
    float v = (n < H1) ? ew1[(size_t)l * 257 * H1 + (size_t)k * H1 + n] : 0.f;
    w1b[(size_t)(l * H1P + n) * 256 + (k ^ ((n & 7) << 3))] = f2bf(v);
    if (k == 0) {
        bias2[(l * H1P + n) * 2 + 0] = (n < H1) ? eb1[l * H1 + n] : 0.f;
        bias2[(l * H1P + n) * 2 + 1] = (n < H1) ? ew1[(size_t)l * 257 * H1 + (size_t)256 * H1 + n] : 0.f;
    }
}

// w2b[l][n<64][k<544] (1088B rows)
__global__ void prep_w2(const float* __restrict__ ew2, u16* __restrict__ w2b) {
    int i = blockIdx.x * 256 + threadIdx.x;
    if (i >= 3 * 64 * H1P) return;
    int k = i % H1P;
    int n = (i / H1P) & 63;
    int l = i / (H1P * 64);
    float v = (k < H1) ? ew2[(size_t)l * H1 * 64 + (size_t)k * 64 + n] : 0.f;
    w2b[(size_t)(l * 64 + n) * H1P + k] = f2bf(v);
}

// cw1b[l][n<256][k<64] (128B rows)
__global__ void prep_cw1(const float* __restrict__ cw1, u16* __restrict__ cw1b) {
    int i = blockIdx.x * 256 + threadIdx.x;
    if (i >= 3 * 256 * 64) return;
    int k = i & 63;
    int n = (i >> 6) & 255;
    int l = i >> 14;
    cw1b[(size_t)l * 16384 + n * 64 + k] = f2bf(cw1[(size_t)l * 16384 + k * 256 + n]);
}

// nw1b[l][n<256][k<192]
__global__ void prep_nw1(const float* __restrict__ nw1, u16* __restrict__ nw1b) {
    int i = blockIdx.x * 256 + threadIdx.x;
    if (i >= 3 * 256 * 192) return;
    int k = i % 192;
    int n = (i / 192) & 255;
    int l = i / (192 * 256);
    nw1b[(size_t)(l * 256 + n) * 192 + k] = f2bf(nw1[(size_t)l * 192 * 256 + (size_t)k * 256 + n]);
}

// nw2b[l][n<128][k<256]
__global__ void prep_nw2(const float* __restrict__ nw2, u16* __restrict__ nw2b) {
    int i = blockIdx.x * 256 + threadIdx.x;
    if (i >= 3 * 128 * 256) return;
    int k = i & 255;
    int n = (i >> 8) & 127;
    int l = i >> 15;
    nw2b[(size_t)(l * 128 + n) * 256 + k] = f2bf(nw2[(size_t)l * 256 * 128 + (size_t)k * 128 + n]);
}

// feats fp32 -> bf16 copy: xbf[node][128] bf16 (NN*64 u32 = NN*256 BYTES)
__global__ void x2bf(const float* __restrict__ xc, u32* __restrict__ xbf) {
    int i = blockIdx.x * 256 + threadIdx.x;   // NN*64
    if (i >= NN * 64) return;
    const int node = i >> 6, p = i & 63;
    const float a = xc[(size_t)node * XD + 3 + 2 * p];
    const float b = xc[(size_t)node * XD + 4 + 2 * p];
    xbf[(size_t)node * 64 + p] = pk2(a, b);
}

// ---------------- fused edge kernel: gather staging + W1 double-buffer ----------------
// 128 edges/block, 4 waves; wave owns 32 edges (2 tiles of 16).
// D[m=edge][n=col]: A = e_in fragments (regs), B = W1 chunk (LDS dbuf).

__global__ __launch_bounds__(256, 3) void edge_mfma(
    const float* __restrict__ x, const u16* __restrict__ xbf, const int* __restrict__ eidx,
    const char* __restrict__ w1b, const float* __restrict__ bias2,
    const char* __restrict__ w2b, const float* __restrict__ eb2,
    const char* __restrict__ cw1b, const float* __restrict__ cb1,
    const float* __restrict__ cw2, const float* __restrict__ cb2,
    float* __restrict__ m_i, float* __restrict__ mhat)
{
    // [0,32768): e_in STG (prologue, per-wave 8KB) -> W1 dbuf 2x16KB (loop)
    //            -> MJ (tail only, per-wave 4352B, after barrier)
    // [32768,43008): HT per-wave 2560B   [43008,45056): RDS 128x16B
    // [45056,45568): SDS 128x4B
    __shared__ __align__(16) char LDS[45568];
    const int tid = threadIdx.x;
    const int w = tid >> 6, l = tid & 63, lg = l >> 4, lc = l & 15;
    const int ebase = blockIdx.x * 128 + w * 32;
    char*  HT  = LDS + 32768 + w * 2560;
    char*  MJ  = LDS + w * 4352;
    float* RDS = (float*)(LDS + 43008);
    int*   SDS = (int*)(LDS + 45056);
    char*  STG = LDS + w * 8192;

    // ---- per-edge geometry (lanes l<32 each handle one edge of this wave)
    if (l < 32) {
        const int e = ebase + l;
        const int s = eidx[e], d = eidx[NE + e];
        const float ax = x[(size_t)s * XD + 0] - x[(size_t)d * XD + 0];
        const float ay = x[(size_t)s * XD + 1] - x[(size_t)d * XD + 1];
        const float az = x[(size_t)s * XD + 2] - x[(size_t)d * XD + 2];
        f32x4 v = {ax, ay, az, ax * ax + ay * ay + az * az};
        *(f32x4*)(RDS + (w * 32 + l) * 4) = v;
        SDS[w * 32 + l] = d;
    }

    // ---- stage e_in (p0: feats[dst] k0..127, p1: feats[src] k128..255) via
    //      global_load_lds with source-side XOR swizzle; extract A fragments.
    //      Wave-private region; only wave-local waits needed.
    bf16x8 A[2][8];
    const int r4 = l >> 4;
    #pragma unroll
    for (int p = 0; p < 2; ++p) {
        const int ebs = (p ? 0 : NE) + ebase;
        #pragma unroll
        for (int j = 0; j < 8; ++j) {
            const int r = j * 4 + r4;
            const int node = eidx[ebs + r];
            const int cp = lc ^ (r & 7);
            __builtin_amdgcn_global_load_lds((const GAS u32*)(xbf + (size_t)node * 128 + cp * 8),
                                             (LAS u32*)(STG + j * 1024), 16, 0, 0);
        }
        VM0;
        #pragma unroll
        for (int kt = 0; kt < 4; ++kt)
            #pragma unroll
            for (int et = 0; et < 2; ++et) {
                const int R = et * 16 + lc;
                A[et][p * 4 + kt] = *(bf16x8*)(STG + R * 256 + ((kt * 64 + lg * 16) ^ ((R & 7) << 4)));
            }
        LGKM0;   // frag reads done before region overwrite / reuse
    }

    // rel_dist per accumulator row (chunk-invariant)
    float rdv[2][4];
    #pragma unroll
    for (int mt = 0; mt < 2; ++mt)
        #pragma unroll
        for (int r = 0; r < 4; ++r)
            rdv[mt][r] = RDS[(w * 32 + mt * 16 + lg * 4 + r) * 4 + 3];

    __syncthreads();   // staging region free -> becomes W1 double-buffer

    // ---- m_ij accumulators, bias init
    f32x4 c2[2][4];
    #pragma unroll
    for (int nt = 0; nt < 4; ++nt) {
        const float b = eb2[nt * 16 + lc];
        c2[0][nt] = (f32x4){b, b, b, b};
        c2[1][nt] = (f32x4){b, b, b, b};
    }

    // prologue: stage chunk 0 into buf0 (per-wave 4KB quarter)
    {
        const char* g = w1b + (size_t)w * 4096;
        #pragma unroll
        for (int r = 0; r < 4; ++r)
            __builtin_amdgcn_global_load_lds((const GAS u32*)(g + r * 1024 + l * 16),
                                             (LAS u32*)(LDS + w * 4096 + r * 1024), 16, 0, 0);
    }

    const float* pB = bias2;
    #pragma unroll 1
    for (int ch = 0; ch < NCH; ++ch) {
        VM0;               // own stage(ch) writes complete (issued one full phase ago)
        __syncthreads();   // all waves' quarters visible; prior reads of other buf done
        if (ch + 1 < NCH) {
            const char* g = w1b + (size_t)(ch + 1) * 16384 + w * 4096;
            char* dst = LDS + ((ch + 1) & 1) * 16384 + w * 4096;
            #pragma unroll
            for (int r = 0; r < 4; ++r)
                __builtin_amdgcn_global_load_lds((const GAS u32*)(g + r * 1024 + l * 16),
                                                 (LAS u32*)(dst + r * 1024), 16, 0, 0);
        }
        char* Bc = LDS + (ch & 1) * 16384;

        // MLP1: two 16-col tiles
        #pragma unroll
        for (int nt = 0; nt < 2; ++nt) {
            const float2 bw = *(const float2*)(pB + (nt * 16 + lc) * 2);  // {bias, w_last}
            f32x4 c1[2];
            #pragma unroll
            for (int mt = 0; mt < 2; ++mt)
                #pragma unroll
                for (int r = 0; r < 4; ++r)
                    c1[mt][r] = fmaf(rdv[mt][r], bw.y, bw.x);
            const int nl = nt * 16 + lc;
            #pragma unroll
            for (int kt = 0; kt < 8; ++kt) {
                bf16x8 B = *(bf16x8*)(Bc + nl * 512 + ((kt * 64 + lg * 16) ^ ((nl & 7) << 4)));
                c1[0] = mfma16(A[0][kt], B, c1[0]);
                c1[1] = mfma16(A[1][kt], B, c1[1]);
            }
            #pragma unroll
            for (int mt = 0; mt < 2; ++mt)
                #pragma unroll
                for (int r = 0; r < 4; ++r)
                    *(u16*)(HT + (mt * 16 + lg * 4 + r) * 80 + nl * 2) = bfc(silu(c1[mt][r]));
        }
        LGKM0;
        // MLP2 partial accumulate: A2 = h from HT (wave-private), B = W2 fragment from L2
        bf16x8 A2[2];
        A2[0] = *(bf16x8*)(HT + lc * 80 + lg * 16);
        A2[1] = *(bf16x8*)(HT + (16 + lc) * 80 + lg * 16);
        #pragma unroll
        for (int nt = 0; nt < 4; ++nt) {
            bf16x8 Bw = __builtin_bit_cast(bf16x8,
                *(const u32x4*)(w2b + (size_t)(nt * 16 + lc) * 1088 + ch * 64 + lg * 16));
            c2[0][nt] = mfma16(A2[0], Bw, c2[0][nt]);
            c2[1][nt] = mfma16(A2[1], Bw, c2[1][nt]);
        }
        pB += 64;
    }

    __syncthreads();   // all waves done reading W1 dbuf; MJ overlays that region

    // ---- tail: silu -> m_ij; atomic scatter m_i; stash bf16 in MJ
    int dstn[2][4];
    #pragma unroll
    for (int mt = 0; mt < 2; ++mt)
        #pragma unroll
        for (int r = 0; r < 4; ++r)
            dstn[mt][r] = SDS[w * 32 + mt * 16 + lg * 4 + r];

    #pragma unroll
    for (int mt = 0; mt < 2; ++mt)
        #pragma unroll
        for (int nt = 0; nt < 4; ++nt)
            #pragma unroll
            for (int r = 0; r < 4; ++r) {
                const float v = silu(c2[mt][nt][r]);
                const int rowl = mt * 16 + lg * 4 + r;
                const int col  = nt * 16 + lc;
                *(u16*)(MJ + rowl * 136 + col * 2) = bfc(v);
                atomicAdd(m_i + (size_t)dstn[mt][r] * 64 + col, v);
            }
    LGKM0;

    // ---- coor MLP: A3 = m_ij (lane=edge), B = cw1 fragment from L2; D3[edge][cc]
    bf16x8 A3[2][2];
    #pragma unroll
    for (int mt = 0; mt < 2; ++mt)
        #pragma unroll
        for (int kt = 0; kt < 2; ++kt)
            A3[mt][kt] = *(bf16x8*)(MJ + (mt * 16 + lc) * 136 + kt * 64 + lg * 16);

    float pw[2][4] = {{0.f, 0.f, 0.f, 0.f}, {0.f, 0.f, 0.f, 0.f}};
    #pragma unroll 4
    for (int ct3 = 0; ct3 < 16; ++ct3) {
        const int col = ct3 * 16 + lc;
        const float b = cb1[col];
        f32x4 c30 = {b, b, b, b}, c31 = {b, b, b, b};
        #pragma unroll
        for (int kt = 0; kt < 2; ++kt) {
            bf16x8 B = __builtin_bit_cast(bf16x8,
                *(const u32x4*)(cw1b + (size_t)col * 128 + kt * 64 + lg * 16));
            c30 = mfma16(A3[0][kt], B, c30);
            c31 = mfma16(A3[1][kt], B, c31);
        }
        const float w2v = cw2[col];
        #pragma unroll
        for (int r = 0; r < 4; ++r) {
            pw[0][r] = fmaf(silu(c30[r]), w2v, pw[0][r]);
            pw[1][r] = fmaf(silu(c31[r]), w2v, pw[1][r]);
        }
    }
    #pragma unroll
    for (int m = 1; m < 16; m <<= 1)
        #pragma unroll
        for (int mt = 0; mt < 2; ++mt)
            #pragma unroll
            for (int r = 0; r < 4; ++r)
                pw[mt][r] += __shfl_xor(pw[mt][r], m, 64);

    const float cb2v = cb2[0];
    if (lc < 3) {
        #pragma unroll
        for (int mt = 0; mt < 2; ++mt)
            #pragma unroll
            for (int r = 0; r < 4; ++r) {
                const int rowl = mt * 16 + lg * 4 + r;
                const float cwv = pw[mt][r] + cb2v;
                atomicAdd(mhat + (size_t)dstn[mt][r] * 3 + lc,
                          cwv * RDS[(w * 32 + rowl) * 4 + lc]);
            }
    }
}

// ---------------- node kernel: LN + MLP via MFMA (passing since R7) ----------------

__global__ __launch_bounds__(256, 2) void node_mfma(
    const float* __restrict__ xc, const float* __restrict__ m_i, const float* __restrict__ mh,
    const float* __restrict__ ng, const float* __restrict__ nb,
    const char* __restrict__ nw1b, const float* __restrict__ nb1,
    const char* __restrict__ nw2b, const float* __restrict__ nb2,
    float* __restrict__ xn)
{
    __shared__ __align__(16) char LDS[4 * 4352];
    const int tid = threadIdx.x;
    const int w = tid >> 6, l = tid & 63, lg = l >> 4, lc = l & 15;
    char* HB = LDS + w * 4352;
    const int nb0 = blockIdx.x * 128 + w * 32;

    int nodes[2]; bool valid[2];
    #pragma unroll
    for (int et = 0; et < 2; ++et) {
        int n = nb0 + et * 16 + lc;
        valid[et] = (n < NN);
        nodes[et] = valid[et] ? n : (NN - 1);
    }

    bf16x8 BF[2][6];
    #pragma unroll
    for (int et = 0; et < 2; ++et) {
        const float* xr = xc + (size_t)nodes[et] * XD + 3;
        float v[4][8];
        float s = 0.f, q = 0.f;
        #pragma unroll
        for (int kt = 0; kt < 4; ++kt) {
            const int k0 = kt * 32 + lg * 8;
            #pragma unroll
            for (int j = 0; j < 8; ++j) {
                const float t = xr[k0 + j];
                v[kt][j] = t; s += t; q = fmaf(t, t, q);
            }
        }
        s += __shfl_xor(s, 16, 64); s += __shfl_xor(s, 32, 64);
        q += __shfl_xor(q, 16, 64); q += __shfl_xor(q, 32, 64);
        const float mu = s * (1.f / 128.f);
        const float rs = rsqrtf(q * (1.f / 128.f) - mu * mu + 1e-5f);
        #pragma unroll
        for (int kt = 0; kt < 4; ++kt) {
            const int k0 = kt * 32 + lg * 8;
            float4 g0 = *(const float4*)(ng + k0), g1 = *(const float4*)(ng + k0 + 4);
            float4 b0 = *(const float4*)(nb + k0), b1 = *(const float4*)(nb + k0 + 4);
            const u32 u0 = pk2((v[kt][0] - mu) * rs * g0.x + b0.x, (v[kt][1] - mu) * rs * g0.y + b0.y);
            const u32 u1 = pk2((v[kt][2] - mu) * rs * g0.z + b0.z, (v[kt][3] - mu) * rs * g0.w + b0.w);
            const u32 u2 = pk2((v[kt][4] - mu) * rs * g1.x + b1.x, (v[kt][5] - mu) * rs * g1.y + b1.y);
            const u32 u3 = pk2((v[kt][6] - mu) * rs * g1.z + b1.z, (v[kt][7] - mu) * rs * g1.w + b1.w);
            BF[et][kt] = mk8(u0, u1, u2, u3);
        }
        const float* mr = m_i + (size_t)nodes[et] * 64;
        #pragma unroll
        for (int kt2 = 0; kt2 < 2; ++kt2) {
            float4 a = *(const float4*)(mr + kt2 * 32 + lg * 8);
            float4 b = *(const float4*)(mr + kt2 * 32 + lg * 8 + 4);
            BF[et][4 + kt2] = mk8(pk2(a.x, a.y), pk2(a.z, a.w), pk2(b.x, b.y), pk2(b.z, b.w));
        }
    }

    f32x4 a2[8][2];
    #pragma unroll
    for (int ct2 = 0; ct2 < 8; ++ct2) {
        f32x4 b = *(const f32x4*)(nb2 + ct2 * 16 + lg * 4);
        a2[ct2][0] = b; a2[ct2][1] = b;
    }

    #pragma unroll 1
    for (int g = 0; g < 4; ++g) {
        f32x4 a1[4][2];
        #pragma unroll
        for (int ct = 0; ct < 4; ++ct) {
            f32x4 b = *(const f32x4*)(nb1 + g * 64 + ct * 16 + lg * 4);
            a1[ct][0] = b; a1[ct][1] = b;
        }
        #pragma unroll
        for (int ct = 0; ct < 4; ++ct)
            #pragma unroll
            for (int kt = 0; kt < 6; ++kt) {
                bf16x8 Aw = __builtin_bit_cast(bf16x8, *(const u32x4*)(
                    nw1b + (size_t)(g * 64 + ct * 16 + lc) * 384 + kt * 64 + lg * 16));
                a1[ct][0] = mfma16(Aw, BF[0][kt], a1[ct][0]);
                a1[ct][1] = mfma16(Aw, BF[1][kt], a1[ct][1]);
            }
        #pragma unroll
        for (int ct = 0; ct < 4; ++ct)
            #pragma unroll
            for (int et = 0; et < 2; ++et) {
                f32x4 c = a1[ct][et];
                u32 v0 = pk2(silu(c[0]), silu(c[1]));
                u32 v1 = pk2(silu(c[2]), silu(c[3]));
                *(u32*)(HB + (et * 16 + lc) * 136 + ct * 32 + lg * 8) = v0;
                *(u32*)(HB + (et * 16 + lc) * 136 + ct * 32 + lg * 8 + 4) = v1;
            }
        LGKM0;
        __builtin_amdgcn_sched_barrier(0);
        bf16x8 B2[2][2];
        #pragma unroll
        for (int et = 0; et < 2; ++et)
            #pragma unroll
            for (int kt2 = 0; kt2 < 2; ++kt2) {
                u32 a = *(u32*)(HB + (et * 16 + lc) * 136 + kt2 * 64 + lg * 16);
                u32 b = *(u32*)(HB + (et * 16 + lc) * 136 + kt2 * 64 + lg * 16 + 4);
                u32 c = *(u32*)(HB + (et * 16 + lc) * 136 + kt2 * 64 + lg * 16 + 8);
                u32 d = *(u32*)(HB + (et * 16 + lc) * 136 + kt2 * 64 + lg * 16 + 12);
                B2[et][kt2] = mk8(a, b, c, d);
            }
        #pragma unroll
        for (int ct2 = 0; ct2 < 8; ++ct2)
            #pragma unroll
            for (int kt2 = 0; kt2 < 2; ++kt2) {
                bf16x8 Aw = __builtin_bit_cast(bf16x8, *(const u32x4*)(
                    nw2b + (size_t)(ct2 * 16 + lc) * 512 + (g * 64 + kt2 * 32 + lg * 8) * 2));
                a2[ct2][0] = mfma16(Aw, B2[0][kt2], a2[ct2][0]);
                a2[ct2][1] = mfma16(Aw, B2[1][kt2], a2[ct2][1]);
            }
        LGKM0;
        __builtin_amdgcn_sched_barrier(0);
    }

    #pragma unroll
    for (int et = 0; et < 2; ++et) {
        if (!valid[et]) continue;
        const size_t nr = (size_t)nodes[et] * XD;
        #pragma unroll
        for (int ct2 = 0; ct2 < 8; ++ct2)
            #pragma unroll
            for (int r = 0; r < 4; ++r) {
                const int col = ct2 * 16 + lg * 4 + r;
                xn[nr + 3 + col] = a2[ct2][et][r] + xc[nr + 3 + col];
            }
    }
    for (int idx = tid; idx < 384; idx += 256) {
        const int n = blockIdx.x * 128 + idx / 3;
        const int d = idx - (idx / 3) * 3;
        if (n < NN)
            xn[(size_t)n * XD + d] = xc[(size_t)n * XD + d] + mh[n * 3 + d];
    }
}

// ---------------- launch ----------------

extern "C" void kernel_launch(void* const* d_in, const int* in_sizes, int n_in,
                              void* d_out, int out_size, void* d_ws, size_t ws_size,
                              hipStream_t stream) {
    const float* x_in = (const float*)d_in[0];
    const int*   eidx = (const int*)  d_in[1];
    const float* ew1  = (const float*)d_in[2];
    const float* eb1  = (const float*)d_in[3];
    const float* ew2  = (const float*)d_in[4];
    const float* eb2  = (const float*)d_in[5];
    const float* ng   = (const float*)d_in[6];
    const float* nb   = (const float*)d_in[7];
    const float* nw1  = (const float*)d_in[8];
    const float* nb1  = (const float*)d_in[9];
    const float* nw2  = (const float*)d_in[10];
    const float* nb2  = (const float*)d_in[11];
    const float* cw1  = (const float*)d_in[12];
    const float* cb1  = (const float*)d_in[13];
    const float* cw2  = (const float*)d_in[14];
    const float* cb2  = (const float*)d_in[15];
    float* out = (float*)d_out;

    char* ws = (char*)d_ws;
    size_t off = 0;
    auto alloc = [&](size_t bytes) { char* p = ws + off; off = (off + bytes + 255) & ~255ull; return p; };
    float* mi    = (float*)alloc((size_t)NN * MD * 4);       // 5.12 MB
    float* mh    = (float*)alloc((size_t)NN * 3 * 4);        // 0.24 MB
    u32*   xbf   = (u32*)  alloc((size_t)NN * 256);          // NN*64 u32 = NN*256 BYTES
    float* bias2 = (float*)alloc((size_t)3 * H1P * 8);       // {eb1, w1_last} pairs
    char*  w1b   = alloc((size_t)3 * H1P * 512);             // 0.84 MB
    char*  w2b   = alloc((size_t)3 * 64 * 1088);             // 0.21 MB
    char*  cw1b  = alloc((size_t)3 * 256 * 128);             // 0.10 MB
    char*  nw1b  = alloc((size_t)3 * 256 * 384);             // 0.30 MB
    char*  nw2b  = alloc((size_t)3 * 128 * 512);             // 0.20 MB

    prep_w1 <<<(3 * H1P * 256 + 255) / 256, 256, 0, stream>>>(ew1, eb1, (u16*)w1b, bias2);
    prep_w2 <<<(3 * 64 * H1P + 255) / 256, 256, 0, stream>>>(ew2, (u16*)w2b);
    prep_cw1<<<(3 * 256 * 64 + 255) / 256, 256, 0, stream>>>(cw1, (u16*)cw1b);
    prep_nw1<<<(3 * 256 * 192 + 255) / 256, 256, 0, stream>>>(nw1, (u16*)nw1b);
    prep_nw2<<<(3 * 128 * 256 + 255) / 256, 256, 0, stream>>>(nw2, (u16*)nw2b);

    for (int l = 0; l < 3; ++l) {
        // layer I/O: l0 reads x_in, writes d_out; l1/l2 update d_out in place
        const float* xc = (l == 0) ? x_in : out;
        float*       xn = out;
        hipMemsetAsync(mi, 0, (size_t)NN * MD * 4, stream);
        hipMemsetAsync(mh, 0, (size_t)NN * 3 * 4, stream);
        x2bf<<<(NN * 64 + 255) / 256, 256, 0, stream>>>(xc, xbf);
        edge_mfma<<<NE / 128, 256, 0, stream>>>(
            xc, (const u16*)xbf, eidx,
            w1b + (size_t)l * H1P * 512, bias2 + (size_t)l * H1P * 2,
            w2b + (size_t)l * 64 * 1088, eb2 + (size_t)l * 64,
            cw1b + (size_t)l * 256 * 128, cb1 + (size_t)l * 256,
            cw2 + (size_t)l * 256, cb2 + l,
            mi, mh);
        node_mfma<<<(NN + 127) / 128, 256, 0, stream>>>(
            xc, mi, mh,
            ng + (size_t)l * F, nb + (size_t)l * F,
            nw1b + (size_t)l * 256 * 384, nb1 + (size_t)l * 256,
            nw2b + (size_t)l * 128 * 512, nb2 + (size_t)l * F,
            xn);
    }
}

// Round 9
// 804.850 us; speedup vs baseline: 2.8040x; 1.3231x over previous
//
#include <hip/hip_runtime.h>

typedef unsigned short u16;
typedef unsigned int   u32;
typedef __attribute__((ext_vector_type(2))) u32  u32x2;
typedef __attribute__((ext_vector_type(4))) u32  u32x4;
typedef __attribute__((ext_vector_type(8))) __bf16 bf16x8;
typedef __attribute__((ext_vector_type(4))) float  f32x4;

#define NN 20000
#define NE 320000
#define XD 131
#define F  128
#define MD 64
#define H1 514
#define H1P 544
#define NCH 17

#define GAS __attribute__((address_space(1)))
#define LAS __attribute__((address_space(3)))
#define LGKM0 asm volatile("s_waitcnt lgkmcnt(0)" ::: "memory")
#define VM0   asm volatile("s_waitcnt vmcnt(0)" ::: "memory")

// fast silu: v_rcp instead of IEEE div sequence (~5 insts vs ~14); rcp err ~1ulp << bf16 eps
__device__ __forceinline__ float silu(float a) {
    float e = __expf(-a);
    return a * __builtin_amdgcn_rcpf(1.0f + e);
}

__device__ __forceinline__ u16 f2bf(float f) {   // fp32 -> bf16 RNE
    u32 u = __builtin_bit_cast(u32, f);
    return (u16)((u + 0x7FFFu + ((u >> 16) & 1u)) >> 16);
}
__device__ __forceinline__ u16 bfc(float f) { return __builtin_bit_cast(u16, (__bf16)f); }
__device__ __forceinline__ u32 pk2(float a, float b) {
    return (u32)bfc(a) | ((u32)bfc(b) << 16);
}
__device__ __forceinline__ bf16x8 mk8(u32 a, u32 b, u32 c, u32 d) {
    u32x4 t = {a, b, c, d};
    return __builtin_bit_cast(bf16x8, t);
}
__device__ __forceinline__ f32x4 mfma16(bf16x8 a, bf16x8 b, f32x4 c) {
    return __builtin_amdgcn_mfma_f32_16x16x32_bf16(a, b, c, 0, 0, 0);
}

// ---------------- weight prep ----------------

// w1b[l][n<544][k<256] 512B rows, elem k stored at k ^ ((n&7)<<3)  (XOR pre-swizzle)
// bias2[l][n] = {eb1[n], w1_row256[n]}
__global__ void prep_w1(const float* __restrict__ ew1, const float* __restrict__ eb1,
                        u16* __restrict__ w1b, float* __restrict__ bias2) {
    int i = blockIdx.x * 256 + threadIdx.x;
    if (i >= 3 * H1P * 256) return;
    int k = i & 255;
    int n = (i >> 8) % H1P;
    int l = (i >> 8) / H1P;
    float v = (n < H1) ? ew1[(size_t)l * 257 * H1 + (size_t)k * H1 + n] : 0.f;
    w1b[(size_t)(l * H1P + n) * 256 + (k ^ ((n & 7) << 3))] = f2bf(v);
    if (k == 0) {
        bias2[(l * H1P + n) * 2 + 0] = (n < H1) ? eb1[l * H1 + n] : 0.f;
        bias2[(l * H1P + n) * 2 + 1] = (n < H1) ? ew1[(size_t)l * 257 * H1 + (size_t)256 * H1 + n] : 0.f;
    }
}

// w2b[l][n<64][k<544] (1088B rows)
__global__ void prep_w2(const float* __restrict__ ew2, u16* __restrict__ w2b) {
    int i = blockIdx.x * 256 + threadIdx.x;
    if (i >= 3 * 64 * H1P) return;
    int k = i % H1P;
    int n = (i / H1P) & 63;
    int l = i / (H1P * 64);
    float v = (k < H1) ? ew2[(size_t)l * H1 * 64 + (size_t)k * 64 + n] : 0.f;
    w2b[(size_t)(l * 64 + n) * H1P + k] = f2bf(v);
}

// cw1b[l][n<256][k<64] (128B rows)
__global__ void prep_cw1(const float* __restrict__ cw1, u16* __restrict__ cw1b) {
    int i = blockIdx.x * 256 + threadIdx.x;
    if (i >= 3 * 256 * 64) return;
    int k = i & 63;
    int n = (i >> 6) & 255;
    int l = i >> 14;
    cw1b[(size_t)l * 16384 + n * 64 + k] = f2bf(cw1[(size_t)l * 16384 + k * 256 + n]);
}

// nw1b[l][n<256][k<192]
__global__ void prep_nw1(const float* __restrict__ nw1, u16* __restrict__ nw1b) {
    int i = blockIdx.x * 256 + threadIdx.x;
    if (i >= 3 * 256 * 192) return;
    int k = i % 192;
    int n = (i / 192) & 255;
    int l = i / (192 * 256);
    nw1b[(size_t)(l * 256 + n) * 192 + k] = f2bf(nw1[(size_t)l * 192 * 256 + (size_t)k * 256 + n]);
}

// nw2b[l][n<128][k<256]
__global__ void prep_nw2(const float* __restrict__ nw2, u16* __restrict__ nw2b) {
    int i = blockIdx.x * 256 + threadIdx.x;
    if (i >= 3 * 128 * 256) return;
    int k = i & 255;
    int n = (i >> 8) & 127;
    int l = i >> 15;
    nw2b[(size_t)(l * 128 + n) * 256 + k] = f2bf(nw2[(size_t)l * 256 * 128 + (size_t)k * 128 + n]);
}

// feats fp32 -> bf16 copy: xbf[node][128] bf16 (NN*64 u32 = NN*256 BYTES)
__global__ void x2bf(const float* __restrict__ xc, u32* __restrict__ xbf) {
    int i = blockIdx.x * 256 + threadIdx.x;   // NN*64
    if (i >= NN * 64) return;
    const int node = i >> 6, p = i & 63;
    const float a = xc[(size_t)node * XD + 3 + 2 * p];
    const float b = xc[(size_t)node * XD + 4 + 2 * p];
    xbf[(size_t)node * 64 + p] = pk2(a, b);
}

// ---------------- fused edge kernel: gather staging + W1 double-buffer ----------------
// 128 edges/block, 4 waves; wave owns 32 edges (2 tiles of 16).
// MLP1 SWAPPED: D1[m=h-col][n=edge] = W1(as A) x e_in^T(as B) — operand layouts are
// symmetric (row/col=lane&15, k=(lane>>4)*8+j), so fragment reads are unchanged;
// each lane then owns 4 consecutive h-cols of ONE edge -> b64 h-writes.

__global__ __launch_bounds__(256, 3) void edge_mfma(
    const float* __restrict__ x, const u16* __restrict__ xbf, const int* __restrict__ eidx,
    const char* __restrict__ w1b, const float* __restrict__ bias2,
    const char* __restrict__ w2b, const float* __restrict__ eb2,
    const char* __restrict__ cw1b, const float* __restrict__ cb1,
    const float* __restrict__ cw2, const float* __restrict__ cb2,
    float* __restrict__ m_i, float* __restrict__ mhat)
{
    // [0,32768): e_in STG (prologue, per-wave 8KB) -> W1 dbuf 2x16KB (loop)
    //            -> MJ (tail only, per-wave 4352B, after barrier)
    // [32768,43008): HT per-wave 2560B (32 rows x 80B)
    // [43008,45056): RDS 128x16B   [45056,45568): SDS 128x4B
    __shared__ __align__(16) char LDS[45568];
    const int tid = threadIdx.x;
    const int w = tid >> 6, l = tid & 63, lg = l >> 4, lc = l & 15;
    const int ebase = blockIdx.x * 128 + w * 32;
    char*  HT  = LDS + 32768 + w * 2560;
    char*  MJ  = LDS + w * 4352;
    float* RDS = (float*)(LDS + 43008);
    int*   SDS = (int*)(LDS + 45056);
    char*  STG = LDS + w * 8192;

    // ---- per-edge geometry (lanes l<32 each handle one edge of this wave)
    if (l < 32) {
        const int e = ebase + l;
        const int s = eidx[e], d = eidx[NE + e];
        const float ax = x[(size_t)s * XD + 0] - x[(size_t)d * XD + 0];
        const float ay = x[(size_t)s * XD + 1] - x[(size_t)d * XD + 1];
        const float az = x[(size_t)s * XD + 2] - x[(size_t)d * XD + 2];
        f32x4 v = {ax, ay, az, ax * ax + ay * ay + az * az};
        *(f32x4*)(RDS + (w * 32 + l) * 4) = v;
        SDS[w * 32 + l] = d;
    }

    // ---- stage e_in (p0: feats[dst] k0..127, p1: feats[src] k128..255) via
    //      global_load_lds with source-side XOR swizzle; extract fragments.
    bf16x8 A[2][8];
    const int r4 = l >> 4;
    #pragma unroll
    for (int p = 0; p < 2; ++p) {
        const int ebs = (p ? 0 : NE) + ebase;
        #pragma unroll
        for (int j = 0; j < 8; ++j) {
            const int r = j * 4 + r4;
            const int node = eidx[ebs + r];
            const int cp = lc ^ (r & 7);
            __builtin_amdgcn_global_load_lds((const GAS u32*)(xbf + (size_t)node * 128 + cp * 8),
                                             (LAS u32*)(STG + j * 1024), 16, 0, 0);
        }
        VM0;
        #pragma unroll
        for (int kt = 0; kt < 4; ++kt)
            #pragma unroll
            for (int et = 0; et < 2; ++et) {
                const int R = et * 16 + lc;
                A[et][p * 4 + kt] = *(bf16x8*)(STG + R * 256 + ((kt * 64 + lg * 16) ^ ((R & 7) << 4)));
            }
        LGKM0;   // frag reads done before region overwrite / reuse
    }

    // rel_dist per lane's edge (edge = et*16+lc), chunk-invariant
    float rd_e[2];
    rd_e[0] = RDS[(w * 32 + lc) * 4 + 3];
    rd_e[1] = RDS[(w * 32 + 16 + lc) * 4 + 3];
    LGKM0;

    __syncthreads();   // staging region free -> becomes W1 double-buffer

    // ---- m_ij accumulators, bias init (D2[m=edge][n=mijcol], unchanged)
    f32x4 c2[2][4];
    #pragma unroll
    for (int nt = 0; nt < 4; ++nt) {
        const float b = eb2[nt * 16 + lc];
        c2[0][nt] = (f32x4){b, b, b, b};
        c2[1][nt] = (f32x4){b, b, b, b};
    }

    // prologue: stage chunk 0 into buf0 (per-wave 4KB quarter)
    {
        const char* g = w1b + (size_t)w * 4096;
        #pragma unroll
        for (int r = 0; r < 4; ++r)
            __builtin_amdgcn_global_load_lds((const GAS u32*)(g + r * 1024 + l * 16),
                                             (LAS u32*)(LDS + w * 4096 + r * 1024), 16, 0, 0);
    }

    const float* pB = bias2;
    #pragma unroll 1
    for (int ch = 0; ch < NCH; ++ch) {
        VM0;               // own stage(ch) writes complete (issued one full phase ago)
        __syncthreads();   // all waves' quarters visible; prior reads of other buf done
        if (ch + 1 < NCH) {
            const char* g = w1b + (size_t)(ch + 1) * 16384 + w * 4096;
            char* dst = LDS + ((ch + 1) & 1) * 16384 + w * 4096;
            #pragma unroll
            for (int r = 0; r < 4; ++r)
                __builtin_amdgcn_global_load_lds((const GAS u32*)(g + r * 1024 + l * 16),
                                                 (LAS u32*)(dst + r * 1024), 16, 0, 0);
        }
        char* Bc = LDS + (ch & 1) * 16384;

        // MLP1 (swapped): two 16-row (h-col) tiles; lane -> h-cols nt*16+lg*4+r, edge et*16+lc
        #pragma unroll
        for (int nt = 0; nt < 2; ++nt) {
            const float* bp = pB + (nt * 16 + lg * 4) * 2;   // {bias, w_last} pairs, rows lg*4..+3
            f32x4 q0 = *(const f32x4*)(bp);
            f32x4 q1 = *(const f32x4*)(bp + 4);
            f32x4 c10, c11;
            c10[0] = fmaf(rd_e[0], q0[1], q0[0]); c10[1] = fmaf(rd_e[0], q0[3], q0[2]);
            c10[2] = fmaf(rd_e[0], q1[1], q1[0]); c10[3] = fmaf(rd_e[0], q1[3], q1[2]);
            c11[0] = fmaf(rd_e[1], q0[1], q0[0]); c11[1] = fmaf(rd_e[1], q0[3], q0[2]);
            c11[2] = fmaf(rd_e[1], q1[1], q1[0]); c11[3] = fmaf(rd_e[1], q1[3], q1[2]);
            const int nl = nt * 16 + lc;
            #pragma unroll
            for (int kt = 0; kt < 8; ++kt) {
                bf16x8 Wf = *(bf16x8*)(Bc + nl * 512 + ((kt * 64 + lg * 16) ^ ((nl & 7) << 4)));
                c10 = mfma16(Wf, A[0][kt], c10);   // D[h-col][edge]
                c11 = mfma16(Wf, A[1][kt], c11);
            }
            u32x2 v0, v1;
            v0[0] = pk2(silu(c10[0]), silu(c10[1])); v0[1] = pk2(silu(c10[2]), silu(c10[3]));
            v1[0] = pk2(silu(c11[0]), silu(c11[1])); v1[1] = pk2(silu(c11[2]), silu(c11[3]));
            *(u32x2*)(HT + lc * 80 + nt * 32 + lg * 8) = v0;          // edge lc, cols nt*16+lg*4..+3
            *(u32x2*)(HT + (16 + lc) * 80 + nt * 32 + lg * 8) = v1;   // edge 16+lc
        }
        LGKM0;
        // MLP2 partial accumulate: A2 = h from HT (wave-private), B = W2 fragment from L2
        bf16x8 A2[2];
        A2[0] = *(bf16x8*)(HT + lc * 80 + lg * 16);
        A2[1] = *(bf16x8*)(HT + (16 + lc) * 80 + lg * 16);
        #pragma unroll
        for (int nt = 0; nt < 4; ++nt) {
            bf16x8 Bw = __builtin_bit_cast(bf16x8,
                *(const u32x4*)(w2b + (size_t)(nt * 16 + lc) * 1088 + ch * 64 + lg * 16));
            c2[0][nt] = mfma16(A2[0], Bw, c2[0][nt]);
            c2[1][nt] = mfma16(A2[1], Bw, c2[1][nt]);
        }
        pB += 64;
    }

    __syncthreads();   // all waves done reading W1 dbuf; MJ overlays that region

    // ---- tail: silu -> m_ij; atomic scatter m_i; stash bf16 in MJ
    int dstn[2][4];
    #pragma unroll
    for (int mt = 0; mt < 2; ++mt)
        #pragma unroll
        for (int r = 0; r < 4; ++r)
            dstn[mt][r] = SDS[w * 32 + mt * 16 + lg * 4 + r];

    #pragma unroll
    for (int mt = 0; mt < 2; ++mt)
        #pragma unroll
        for (int nt = 0; nt < 4; ++nt)
            #pragma unroll
            for (int r = 0; r < 4; ++r) {
                const float v = silu(c2[mt][nt][r]);
                const int rowl = mt * 16 + lg * 4 + r;
                const int col  = nt * 16 + lc;
                *(u16*)(MJ + rowl * 136 + col * 2) = bfc(v);
                atomicAdd(m_i + (size_t)dstn[mt][r] * 64 + col, v);
            }
    LGKM0;

    // ---- coor MLP: A3 = m_ij (lane=edge), B = cw1 fragment from L2
    bf16x8 A3[2][2];
    #pragma unroll
    for (int mt = 0; mt < 2; ++mt)
        #pragma unroll
        for (int kt = 0; kt < 2; ++kt)
            A3[mt][kt] = *(bf16x8*)(MJ + (mt * 16 + lc) * 136 + kt * 64 + lg * 16);

    float pw[2][4] = {{0.f, 0.f, 0.f, 0.f}, {0.f, 0.f, 0.f, 0.f}};
    #pragma unroll 4
    for (int ct3 = 0; ct3 < 16; ++ct3) {
        const int col = ct3 * 16 + lc;
        const float b = cb1[col];
        f32x4 c30 = {b, b, b, b}, c31 = {b, b, b, b};
        #pragma unroll
        for (int kt = 0; kt < 2; ++kt) {
            bf16x8 B = __builtin_bit_cast(bf16x8,
                *(const u32x4*)(cw1b + (size_t)col * 128 + kt * 64 + lg * 16));
            c30 = mfma16(A3[0][kt], B, c30);
            c31 = mfma16(A3[1][kt], B, c31);
        }
        const float w2v = cw2[col];
        #pragma unroll
        for (int r = 0; r < 4; ++r) {
            pw[0][r] = fmaf(silu(c30[r]), w2v, pw[0][r]);
            pw[1][r] = fmaf(silu(c31[r]), w2v, pw[1][r]);
        }
    }
    #pragma unroll
    for (int m = 1; m < 16; m <<= 1)
        #pragma unroll
        for (int mt = 0; mt < 2; ++mt)
            #pragma unroll
            for (int r = 0; r < 4; ++r)
                pw[mt][r] += __shfl_xor(pw[mt][r], m, 64);

    const float cb2v = cb2[0];
    if (lc < 3) {
        #pragma unroll
        for (int mt = 0; mt < 2; ++mt)
            #pragma unroll
            for (int r = 0; r < 4; ++r) {
                const int rowl = mt * 16 + lg * 4 + r;
                const float cwv = pw[mt][r] + cb2v;
                atomicAdd(mhat + (size_t)dstn[mt][r] * 3 + lc,
                          cwv * RDS[(w * 32 + rowl) * 4 + lc]);
            }
    }
}

// ---------------- node kernel: LN + MLP via MFMA (passing since R7) ----------------

__global__ __launch_bounds__(256, 2) void node_mfma(
    const float* __restrict__ xc, const float* __restrict__ m_i, const float* __restrict__ mh,
    const float* __restrict__ ng, const float* __restrict__ nb,
    const char* __restrict__ nw1b, const float* __restrict__ nb1,
    const char* __restrict__ nw2b, const float* __restrict__ nb2,
    float* __restrict__ xn)
{
    __shared__ __align__(16) char LDS[4 * 4352];
    const int tid = threadIdx.x;
    const int w = tid >> 6, l = tid & 63, lg = l >> 4, lc = l & 15;
    char* HB = LDS + w * 4352;
    const int nb0 = blockIdx.x * 128 + w * 32;

    int nodes[2]; bool valid[2];
    #pragma unroll
    for (int et = 0; et < 2; ++et) {
        int n = nb0 + et * 16 + lc;
        valid[et] = (n < NN);
        nodes[et] = valid[et] ? n : (NN - 1);
    }

    bf16x8 BF[2][6];
    #pragma unroll
    for (int et = 0; et < 2; ++et) {
        const float* xr = xc + (size_t)nodes[et] * XD + 3;
        float v[4][8];
        float s = 0.f, q = 0.f;
        #pragma unroll
        for (int kt = 0; kt < 4; ++kt) {
            const int k0 = kt * 32 + lg * 8;
            #pragma unroll
            for (int j = 0; j < 8; ++j) {
                const float t = xr[k0 + j];
                v[kt][j] = t; s += t; q = fmaf(t, t, q);
            }
        }
        s += __shfl_xor(s, 16, 64); s += __shfl_xor(s, 32, 64);
        q += __shfl_xor(q, 16, 64); q += __shfl_xor(q, 32, 64);
        const float mu = s * (1.f / 128.f);
        const float rs = rsqrtf(q * (1.f / 128.f) - mu * mu + 1e-5f);
        #pragma unroll
        for (int kt = 0; kt < 4; ++kt) {
            const int k0 = kt * 32 + lg * 8;
            float4 g0 = *(const float4*)(ng + k0), g1 = *(const float4*)(ng + k0 + 4);
            float4 b0 = *(const float4*)(nb + k0), b1 = *(const float4*)(nb + k0 + 4);
            const u32 u0 = pk2((v[kt][0] - mu) * rs * g0.x + b0.x, (v[kt][1] - mu) * rs * g0.y + b0.y);
            const u32 u1 = pk2((v[kt][2] - mu) * rs * g0.z + b0.z, (v[kt][3] - mu) * rs * g0.w + b0.w);
            const u32 u2 = pk2((v[kt][4] - mu) * rs * g1.x + b1.x, (v[kt][5] - mu) * rs * g1.y + b1.y);
            const u32 u3 = pk2((v[kt][6] - mu) * rs * g1.z + b1.z, (v[kt][7] - mu) * rs * g1.w + b1.w);
            BF[et][kt] = mk8(u0, u1, u2, u3);
        }
        const float* mr = m_i + (size_t)nodes[et] * 64;
        #pragma unroll
        for (int kt2 = 0; kt2 < 2; ++kt2) {
            float4 a = *(const float4*)(mr + kt2 * 32 + lg * 8);
            float4 b = *(const float4*)(mr + kt2 * 32 + lg * 8 + 4);
            BF[et][4 + kt2] = mk8(pk2(a.x, a.y), pk2(a.z, a.w), pk2(b.x, b.y), pk2(b.z, b.w));
        }
    }

    f32x4 a2[8][2];
    #pragma unroll
    for (int ct2 = 0; ct2 < 8; ++ct2) {
        f32x4 b = *(const f32x4*)(nb2 + ct2 * 16 + lg * 4);
        a2[ct2][0] = b; a2[ct2][1] = b;
    }

    #pragma unroll 1
    for (int g = 0; g < 4; ++g) {
        f32x4 a1[4][2];
        #pragma unroll
        for (int ct = 0; ct < 4; ++ct) {
            f32x4 b = *(const f32x4*)(nb1 + g * 64 + ct * 16 + lg * 4);
            a1[ct][0] = b; a1[ct][1] = b;
        }
        #pragma unroll
        for (int ct = 0; ct < 4; ++ct)
            #pragma unroll
            for (int kt = 0; kt < 6; ++kt) {
                bf16x8 Aw = __builtin_bit_cast(bf16x8, *(const u32x4*)(
                    nw1b + (size_t)(g * 64 + ct * 16 + lc) * 384 + kt * 64 + lg * 16));
                a1[ct][0] = mfma16(Aw, BF[0][kt], a1[ct][0]);
                a1[ct][1] = mfma16(Aw, BF[1][kt], a1[ct][1]);
            }
        #pragma unroll
        for (int ct = 0; ct < 4; ++ct)
            #pragma unroll
            for (int et = 0; et < 2; ++et) {
                f32x4 c = a1[ct][et];
                u32 v0 = pk2(silu(c[0]), silu(c[1]));
                u32 v1 = pk2(silu(c[2]), silu(c[3]));
                *(u32*)(HB + (et * 16 + lc) * 136 + ct * 32 + lg * 8) = v0;
                *(u32*)(HB + (et * 16 + lc) * 136 + ct * 32 + lg * 8 + 4) = v1;
            }
        LGKM0;
        __builtin_amdgcn_sched_barrier(0);
        bf16x8 B2[2][2];
        #pragma unroll
        for (int et = 0; et < 2; ++et)
            #pragma unroll
            for (int kt2 = 0; kt2 < 2; ++kt2) {
                u32 a = *(u32*)(HB + (et * 16 + lc) * 136 + kt2 * 64 + lg * 16);
                u32 b = *(u32*)(HB + (et * 16 + lc) * 136 + kt2 * 64 + lg * 16 + 4);
                u32 c = *(u32*)(HB + (et * 16 + lc) * 136 + kt2 * 64 + lg * 16 + 8);
                u32 d = *(u32*)(HB + (et * 16 + lc) * 136 + kt2 * 64 + lg * 16 + 12);
                B2[et][kt2] = mk8(a, b, c, d);
            }
        #pragma unroll
        for (int ct2 = 0; ct2 < 8; ++ct2)
            #pragma unroll
            for (int kt2 = 0; kt2 < 2; ++kt2) {
                bf16x8 Aw = __builtin_bit_cast(bf16x8, *(const u32x4*)(
                    nw2b + (size_t)(ct2 * 16 + lc) * 512 + (g * 64 + kt2 * 32 + lg * 8) * 2));
                a2[ct2][0] = mfma16(Aw, B2[0][kt2], a2[ct2][0]);
                a2[ct2][1] = mfma16(Aw, B2[1][kt2], a2[ct2][1]);
            }
        LGKM0;
        __builtin_amdgcn_sched_barrier(0);
    }

    #pragma unroll
    for (int et = 0; et < 2; ++et) {
        if (!valid[et]) continue;
        const size_t nr = (size_t)nodes[et] * XD;
        #pragma unroll
        for (int ct2 = 0; ct2 < 8; ++ct2)
            #pragma unroll
            for (int r = 0; r < 4; ++r) {
                const int col = ct2 * 16 + lg * 4 + r;
                xn[nr + 3 + col] = a2[ct2][et][r] + xc[nr + 3 + col];
            }
    }
    for (int idx = tid; idx < 384; idx += 256) {
        const int n = blockIdx.x * 128 + idx / 3;
        const int d = idx - (idx / 3) * 3;
        if (n < NN)
            xn[(size_t)n * XD + d] = xc[(size_t)n * XD + d] + mh[n * 3 + d];
    }
}

// ---------------- launch ----------------

extern "C" void kernel_launch(void* const* d_in, const int* in_sizes, int n_in,
                              void* d_out, int out_size, void* d_ws, size_t ws_size,
                              hipStream_t stream) {
    const float* x_in = (const float*)d_in[0];
    const int*   eidx = (const int*)  d_in[1];
    const float* ew1  = (const float*)d_in[2];
    const float* eb1  = (const float*)d_in[3];
    const float* ew2  = (const float*)d_in[4];
    const float* eb2  = (const float*)d_in[5];
    const float* ng   = (const float*)d_in[6];
    const float* nb   = (const float*)d_in[7];
    const float* nw1  = (const float*)d_in[8];
    const float* nb1  = (const float*)d_in[9];
    const float* nw2  = (const float*)d_in[10];
    const float* nb2  = (const float*)d_in[11];
    const float* cw1  = (const float*)d_in[12];
    const float* cb1  = (const float*)d_in[13];
    const float* cw2  = (const float*)d_in[14];
    const float* cb2  = (const float*)d_in[15];
    float* out = (float*)d_out;

    char* ws = (char*)d_ws;
    size_t off = 0;
    auto alloc = [&](size_t bytes) { char* p = ws + off; off = (off + bytes + 255) & ~255ull; return p; };
    float* mi    = (float*)alloc((size_t)NN * MD * 4);       // 5.12 MB
    float* mh    = (float*)alloc((size_t)NN * 3 * 4);        // 0.24 MB
    u32*   xbf   = (u32*)  alloc((size_t)NN * 256);          // NN*64 u32 = NN*256 BYTES
    float* bias2 = (float*)alloc((size_t)3 * H1P * 8);       // {eb1, w1_last} pairs
    char*  w1b   = alloc((size_t)3 * H1P * 512);
    char*  w2b   = alloc((size_t)3 * 64 * 1088);
    char*  cw1b  = alloc((size_t)3 * 256 * 128);
    char*  nw1b  = alloc((size_t)3 * 256 * 384);
    char*  nw2b  = alloc((size_t)3 * 128 * 512);

    prep_w1 <<<(3 * H1P * 256 + 255) / 256, 256, 0, stream>>>(ew1, eb1, (u16*)w1b, bias2);
    prep_w2 <<<(3 * 64 * H1P + 255) / 256, 256, 0, stream>>>(ew2, (u16*)w2b);
    prep_cw1<<<(3 * 256 * 64 + 255) / 256, 256, 0, stream>>>(cw1, (u16*)cw1b);
    prep_nw1<<<(3 * 256 * 192 + 255) / 256, 256, 0, stream>>>(nw1, (u16*)nw1b);
    prep_nw2<<<(3 * 128 * 256 + 255) / 256, 256, 0, stream>>>(nw2, (u16*)nw2b);

    for (int l = 0; l < 3; ++l) {
        // layer I/O: l0 reads x_in, writes d_out; l1/l2 update d_out in place
        const float* xc = (l == 0) ? x_in : out;
        float*       xn = out;
        hipMemsetAsync(mi, 0, (size_t)NN * MD * 4, stream);
        hipMemsetAsync(mh, 0, (size_t)NN * 3 * 4, stream);
        x2bf<<<(NN * 64 + 255) / 256, 256, 0, stream>>>(xc, xbf);
        edge_mfma<<<NE / 128, 256, 0, stream>>>(
            xc, (const u16*)xbf, eidx,
            w1b + (size_t)l * H1P * 512, bias2 + (size_t)l * H1P * 2,
            w2b + (size_t)l * 64 * 1088, eb2 + (size_t)l * 64,
            cw1b + (size_t)l * 256 * 128, cb1 + (size_t)l * 256,
            cw2 + (size_t)l * 256, cb2 + l,
            mi, mh);
        node_mfma<<<(NN + 127) / 128, 256, 0, stream>>>(
            xc, mi, mh,
            ng + (size_t)l * F, nb + (size_t)l * F,
            nw1b + (size_t)l * 256 * 384, nb1 + (size_t)l * 256,
            nw2b + (size_t)l * 128 * 512, nb2 + (size_t)l * F,
            xn);
    }
}